// Round 5
// baseline (241.595 us; speedup 1.0000x reference)
//
#include <hip/hip_runtime.h>
#include <hip/hip_bf16.h>
#include <math.h>

#define NBLK 256   // binning blocks
#define NBS  512   // bucket slots (pow2 bucket = 256 nodes => 391 used)

// ---------------- binned CSR build (no global atomics, pow2 buckets) ----------------
__global__ __launch_bounds__(256) void k_bin_count(const int* __restrict__ ei,
    int E, int ET, int chunk, int* __restrict__ A) {
  __shared__ int lh[NBS];
  int t = threadIdx.x;
  lh[t] = 0; lh[t + 256] = 0;
  __syncthreads();
  int beg = blockIdx.x * chunk, end = min(beg + chunk, ET);
  for (int i = beg + t; i < end; i += 256) {
    int d = (i < E) ? ei[E + i] : (i - E);      // self loop for i>=E
    atomicAdd(&lh[d >> 8], 1);
  }
  __syncthreads();
  A[t * NBLK + blockIdx.x] = lh[t];
  A[(t + 256) * NBLK + blockIdx.x] = lh[t + 256];
}

__global__ void k_reduce(const int* __restrict__ a, int* bsum, int n) {
  int i = blockIdx.x * 256 + threadIdx.x;
  int v = (i < n) ? a[i] : 0;
  #pragma unroll
  for (int off = 32; off; off >>= 1) v += __shfl_down(v, off, 64);
  __shared__ int sh[4];
  if ((threadIdx.x & 63) == 0) sh[threadIdx.x >> 6] = v;
  __syncthreads();
  if (threadIdx.x == 0) bsum[blockIdx.x] = sh[0] + sh[1] + sh[2] + sh[3];
}

__global__ void k_scan_bsum(int* bsum, int nb) {
  __shared__ int sh[512];
  int t = threadIdx.x;
  int v = (t < nb) ? bsum[t] : 0;
  sh[t] = v; __syncthreads();
  for (int off = 1; off < 512; off <<= 1) {
    int add = (t >= off) ? sh[t - off] : 0;
    __syncthreads();
    sh[t] += add;
    __syncthreads();
  }
  if (t < nb) bsum[t] = sh[t] - v;   // exclusive
}

__global__ void k_scan_apply(int* A, const int* __restrict__ bsum, int n) {
  __shared__ int sh[256];
  int t = threadIdx.x; int i = blockIdx.x * 256 + t;
  int v = (i < n) ? A[i] : 0;
  sh[t] = v; __syncthreads();
  for (int off = 1; off < 256; off <<= 1) {
    int add = (t >= off) ? sh[t - off] : 0;
    __syncthreads();
    sh[t] += add;
    __syncthreads();
  }
  int excl = sh[t] - v + bsum[blockIdx.x];
  if (i < n) A[i] = excl;
  if (i == n - 1) A[n] = excl + v;
}

__global__ __launch_bounds__(256) void k_bin_scatter(const int* __restrict__ ei,
    int E, int ET, int chunk, const int* __restrict__ A, int* __restrict__ pairs) {
  __shared__ int cur[NBS];
  int t = threadIdx.x;
  cur[t]       = A[t * NBLK + blockIdx.x];
  cur[t + 256] = A[(t + 256) * NBLK + blockIdx.x];
  __syncthreads();
  int beg = blockIdx.x * chunk, end = min(beg + chunk, ET);
  for (int i = beg + t; i < end; i += 256) {
    int s, d;
    if (i < E) { s = ei[i]; d = ei[E + i]; } else { s = d = i - E; }
    int pos = atomicAdd(&cur[d >> 8], 1);
    pairs[pos] = (s << 8) | (d & 255);        // src<2^24, local dst in 8 bits
  }
}

__global__ __launch_bounds__(256) void k_csr_build(const int* __restrict__ pairs,
    const int* __restrict__ A, int* __restrict__ csr_ptr, int* __restrict__ csr_src,
    int N, int NBu) {
  __shared__ int cnt[256];
  __shared__ int cur[256];
  __shared__ int sh[256];
  int b = blockIdx.x, t = threadIdx.x;
  int base = A[b * NBLK], endp = A[(b + 1) * NBLK];
  int node0 = b << 8;
  cnt[t] = 0;
  __syncthreads();
  for (int e = base + t; e < endp; e += 256)
    atomicAdd(&cnt[pairs[e] & 255], 1);
  __syncthreads();
  int v = cnt[t];
  sh[t] = v; __syncthreads();
  for (int off = 1; off < 256; off <<= 1) {
    int add = (t >= off) ? sh[t - off] : 0;
    __syncthreads();
    sh[t] += add;
    __syncthreads();
  }
  int excl = sh[t] - v;
  if (node0 + t < N) csr_ptr[node0 + t] = base + excl;
  cur[t] = base + excl;
  if (b == NBu - 1 && t == 0) csr_ptr[N] = endp;
  __syncthreads();
  for (int e = base + t; e < endp; e += 256) {
    int p = pairs[e];
    int pos = atomicAdd(&cur[p & 255], 1);
    csr_src[pos] = ((unsigned)p) >> 8;
  }
}

// ---------------- layer 1 transform: xl1 = x@W1l, xr1 = x@W1r ----------------
__global__ __launch_bounds__(256) void k_gemm1(const float* __restrict__ x,
    const float* __restrict__ Wl, const float* __restrict__ Wr,
    float* __restrict__ xl, float* __restrict__ xr, int n) {
  __shared__ float xs[64 * 132];
  __shared__ float Ws[128 * 32];
  int t = threadIdx.x;
  int r0 = blockIdx.x * 64;
  #pragma unroll
  for (int i = 0; i < 8; i++) {
    int idx = t + i * 256;
    int k = idx >> 4, c = idx & 15;
    Ws[k * 32 + c]      = Wl[idx];
    Ws[k * 32 + 16 + c] = Wr[idx];
  }
  #pragma unroll
  for (int i = 0; i < 8; i++) {
    int v = t + i * 256;
    int row = v >> 5;
    int col4 = v & 31;
    float4 val = make_float4(0.f, 0.f, 0.f, 0.f);
    if (r0 + row < n)
      val = reinterpret_cast<const float4*>(x)[(long)(r0 + row) * 32 + col4];
    float* dst = &xs[row * 132 + col4 * 4];
    dst[0] = val.x; dst[1] = val.y; dst[2] = val.z; dst[3] = val.w;
  }
  __syncthreads();
  int g = t >> 2;
  int sub = t & 3;
  float acc[8] = {0.f,0.f,0.f,0.f,0.f,0.f,0.f,0.f};
  #pragma unroll 4
  for (int k = 0; k < 128; k++) {
    float xv = xs[g * 132 + k];
    const float4* wp = reinterpret_cast<const float4*>(&Ws[k * 32 + sub * 8]);
    float4 w0 = wp[0], w1 = wp[1];
    acc[0] += xv * w0.x; acc[1] += xv * w0.y; acc[2] += xv * w0.z; acc[3] += xv * w0.w;
    acc[4] += xv * w1.x; acc[5] += xv * w1.y; acc[6] += xv * w1.z; acc[7] += xv * w1.w;
  }
  int row = r0 + g;
  if (row < n) {
    float* o = (sub < 2) ? &xl[(long)row * 16 + sub * 8]
                         : &xr[(long)row * 16 + (sub - 2) * 8];
    float4* o4 = reinterpret_cast<float4*>(o);
    o4[0] = make_float4(acc[0], acc[1], acc[2], acc[3]);
    o4[1] = make_float4(acc[4], acc[5], acc[6], acc[7]);
  }
}

// ------- layer-1 edge aggregation, lane-per-node, fused layer-2 transform -------
// leaky(z) = 0.6z + 0.4|z| (slope 0.2). Defer-max: m=0 unless e>m+25 (exact fallback).
__global__ __launch_bounds__(256) void k_edge1(const int* __restrict__ csr_ptr,
    const int* __restrict__ csr_src, const float* __restrict__ xl,
    const float* __restrict__ xr, const float* __restrict__ att,
    const float* __restrict__ bias, const float* __restrict__ W2l,
    const float* __restrict__ W2r, float* __restrict__ xl2,
    float* __restrict__ xr2, int n) {
  __shared__ float Wls[128], Wrs[128];
  int t = threadIdx.x;
  if (t < 128) { Wls[t] = W2l[t]; Wrs[t] = W2r[t]; }
  __syncthreads();
  int node = blockIdx.x * 256 + t;
  if (node >= n) return;
  int beg = csr_ptr[node], end = csr_ptr[node + 1];
  float xrv[16], av[16], nu[16];
  const float4* xrp = reinterpret_cast<const float4*>(xr + (long)node * 16);
  #pragma unroll
  for (int q = 0; q < 4; q++) {
    float4 v = xrp[q];
    xrv[q*4] = v.x; xrv[q*4+1] = v.y; xrv[q*4+2] = v.z; xrv[q*4+3] = v.w;
  }
  #pragma unroll
  for (int c = 0; c < 16; c++) { av[c] = att[c]; nu[c] = 0.f; }
  float m = 0.f, s = 0.f;
  #pragma unroll 2
  for (int i = beg; i < end; ++i) {
    int src = csr_src[i];
    float xlv[16];
    const float4* p = reinterpret_cast<const float4*>(xl + (long)src * 16);
    #pragma unroll
    for (int q = 0; q < 4; q++) {
      float4 v = p[q];
      xlv[q*4] = v.x; xlv[q*4+1] = v.y; xlv[q*4+2] = v.z; xlv[q*4+3] = v.w;
    }
    float e1 = 0.f, e2 = 0.f;
    #pragma unroll
    for (int c = 0; c < 16; c++) {
      float z = xlv[c] + xrv[c];
      e1 += av[c] * z;
      e2 += av[c] * fabsf(z);
    }
    float e = 0.6f * e1 + 0.4f * e2;
    if (e > m + 25.f) {                       // rare exact rescale fallback
      float sc = __expf(m - e);
      s *= sc;
      #pragma unroll
      for (int c = 0; c < 16; c++) nu[c] *= sc;
      m = e;
    }
    float pe = __expf(e - m);
    s += pe;
    #pragma unroll
    for (int c = 0; c < 16; c++) nu[c] += pe * xlv[c];
  }
  float inv = 1.f / fmaxf(s, 1e-16f);
  float o[16];
  #pragma unroll
  for (int c = 0; c < 16; c++) o[c] = fmaxf(nu[c] * inv + bias[c], 0.f);  // relu(h1)
  // fused layer-2 transform: xl2 = o@W2l, xr2 = o@W2r
  float l2[8] = {0,0,0,0,0,0,0,0}, r2[8] = {0,0,0,0,0,0,0,0};
  #pragma unroll
  for (int k = 0; k < 16; k++) {
    float ok = o[k];
    #pragma unroll
    for (int j = 0; j < 8; j++) {
      l2[j] += ok * Wls[k * 8 + j];
      r2[j] += ok * Wrs[k * 8 + j];
    }
  }
  float4* pl = reinterpret_cast<float4*>(xl2 + (long)node * 8);
  float4* pr = reinterpret_cast<float4*>(xr2 + (long)node * 8);
  pl[0] = make_float4(l2[0], l2[1], l2[2], l2[3]);
  pl[1] = make_float4(l2[4], l2[5], l2[6], l2[7]);
  pr[0] = make_float4(r2[0], r2[1], r2[2], r2[3]);
  pr[1] = make_float4(r2[4], r2[5], r2[6], r2[7]);
}

// ------- layer-2 edge aggregation, lane-per-node -------
__global__ __launch_bounds__(256) void k_edge2(const int* __restrict__ csr_ptr,
    const int* __restrict__ csr_src, const float* __restrict__ xl,
    const float* __restrict__ xr, const float* __restrict__ att,
    const float* __restrict__ bias, float* __restrict__ out, int n) {
  int node = blockIdx.x * 256 + threadIdx.x;
  if (node >= n) return;
  int beg = csr_ptr[node], end = csr_ptr[node + 1];
  float xrv[8], av[8], nu[8];
  const float4* xrp = reinterpret_cast<const float4*>(xr + (long)node * 8);
  {
    float4 v0 = xrp[0], v1 = xrp[1];
    xrv[0]=v0.x; xrv[1]=v0.y; xrv[2]=v0.z; xrv[3]=v0.w;
    xrv[4]=v1.x; xrv[5]=v1.y; xrv[6]=v1.z; xrv[7]=v1.w;
  }
  #pragma unroll
  for (int c = 0; c < 8; c++) { av[c] = att[c]; nu[c] = 0.f; }
  float m = 0.f, s = 0.f;
  #pragma unroll 2
  for (int i = beg; i < end; ++i) {
    int src = csr_src[i];
    float xlv[8];
    const float4* p = reinterpret_cast<const float4*>(xl + (long)src * 8);
    float4 v0 = p[0], v1 = p[1];
    xlv[0]=v0.x; xlv[1]=v0.y; xlv[2]=v0.z; xlv[3]=v0.w;
    xlv[4]=v1.x; xlv[5]=v1.y; xlv[6]=v1.z; xlv[7]=v1.w;
    float e1 = 0.f, e2 = 0.f;
    #pragma unroll
    for (int c = 0; c < 8; c++) {
      float z = xlv[c] + xrv[c];
      e1 += av[c] * z;
      e2 += av[c] * fabsf(z);
    }
    float e = 0.6f * e1 + 0.4f * e2;
    if (e > m + 25.f) {
      float sc = __expf(m - e);
      s *= sc;
      #pragma unroll
      for (int c = 0; c < 8; c++) nu[c] *= sc;
      m = e;
    }
    float pe = __expf(e - m);
    s += pe;
    #pragma unroll
    for (int c = 0; c < 8; c++) nu[c] += pe * xlv[c];
  }
  float inv = 1.f / fmaxf(s, 1e-16f);
  float4* po = reinterpret_cast<float4*>(out + (long)node * 8);
  float o[8];
  #pragma unroll
  for (int c = 0; c < 8; c++) o[c] = fmaxf(nu[c] * inv + bias[c], 0.f);
  po[0] = make_float4(o[0], o[1], o[2], o[3]);
  po[1] = make_float4(o[4], o[5], o[6], o[7]);
}

// ---------------- fused mean pool + linear: one block per graph ----------------
__global__ __launch_bounds__(256) void k_pool_final(const float* __restrict__ h,
    const int* __restrict__ batch, const float* __restrict__ Wlin,
    const float* __restrict__ blin, float* __restrict__ out, int n) {
  int g = blockIdx.x;
  int lo = 0, hi = n;
  while (lo < hi) { int mid = (lo + hi) >> 1; if (batch[mid] < g) lo = mid + 1; else hi = mid; }
  int beg = lo;
  hi = n;
  while (lo < hi) { int mid = (lo + hi) >> 1; if (batch[mid] < g + 1) lo = mid + 1; else hi = mid; }
  int end = lo;

  float w[8];
  #pragma unroll
  for (int c = 0; c < 8; c++) w[c] = Wlin[c];

  float acc = 0.f;
  int t = threadIdx.x;
  for (int i = beg + t; i < end; i += 256) {
    const float4* hp = reinterpret_cast<const float4*>(h + (long)i * 8);
    float4 v0 = hp[0], v1 = hp[1];
    acc += v0.x * w[0] + v0.y * w[1] + v0.z * w[2] + v0.w * w[3]
         + v1.x * w[4] + v1.y * w[5] + v1.z * w[6] + v1.w * w[7];
  }
  #pragma unroll
  for (int off = 32; off; off >>= 1) acc += __shfl_down(acc, off, 64);
  __shared__ float sh[4];
  if ((t & 63) == 0) sh[t >> 6] = acc;
  __syncthreads();
  if (t == 0) {
    float total = sh[0] + sh[1] + sh[2] + sh[3];
    float cnt = (float)(end - beg);
    out[g] = total / fmaxf(cnt, 1.f) + blin[0];
  }
}

extern "C" void kernel_launch(void* const* d_in, const int* in_sizes, int n_in,
                              void* d_out, int out_size, void* d_ws, size_t ws_size,
                              hipStream_t stream) {
  (void)n_in; (void)ws_size;
  const float* x    = (const float*)d_in[0];
  const int*   ei   = (const int*)d_in[1];
  const int*   batch= (const int*)d_in[2];
  const float* W1l  = (const float*)d_in[3];
  const float* W1r  = (const float*)d_in[4];
  const float* a1   = (const float*)d_in[5];
  const float* b1   = (const float*)d_in[6];
  const float* W2l  = (const float*)d_in[7];
  const float* W2r  = (const float*)d_in[8];
  const float* a2   = (const float*)d_in[9];
  const float* b2   = (const float*)d_in[10];
  const float* Wlin = (const float*)d_in[11];
  const float* blin = (const float*)d_in[12];
  float* out = (float*)d_out;

  int N = in_sizes[0] / 128;
  int E = in_sizes[1] / 2;
  int G = out_size;                 // 256 graphs
  int ET = E + N;                   // edges incl self loops
  int NBu = (N + 255) >> 8;         // used buckets (256 nodes each), <= NBS
  int chunk = (ET + NBLK - 1) / NBLK;
  int nA = NBS * NBLK;              // 131072

  char* ws = (char*)d_ws;
  size_t off = 0;
  auto alloc = [&](size_t bytes) {
    void* p = ws + off; off = (off + bytes + 255) & ~(size_t)255; return p;
  };
  int* csr_ptr = (int*)alloc((size_t)(N + 1) * 4);
  int* A       = (int*)alloc((size_t)(nA + 1) * 4);
  int* bsum    = (int*)alloc(512 * 4);
  int* csr_src = (int*)alloc((size_t)ET * 4);
  // union: packed pairs (ET*4 B) time-shared with feature buffers (N*224 B)
  size_t featBytes = (size_t)N * (16 + 16 + 8 + 8 + 8) * 4;
  size_t pairBytes = (size_t)ET * 4;
  char* u = (char*)alloc(pairBytes > featBytes ? pairBytes : featBytes);
  int* pairs = (int*)u;
  float* xl1 = (float*)u;
  float* xr1 = xl1 + (size_t)N * 16;
  float* xl2 = xr1 + (size_t)N * 16;
  float* xr2 = xl2 + (size_t)N * 8;
  float* h2  = xr2 + (size_t)N * 8;

  k_bin_count<<<NBLK, 256, 0, stream>>>(ei, E, ET, chunk, A);
  k_reduce<<<(nA + 255) / 256, 256, 0, stream>>>(A, bsum, nA);
  k_scan_bsum<<<1, 512, 0, stream>>>(bsum, (nA + 255) / 256);
  k_scan_apply<<<(nA + 255) / 256, 256, 0, stream>>>(A, bsum, nA);
  k_bin_scatter<<<NBLK, 256, 0, stream>>>(ei, E, ET, chunk, A, pairs);
  k_csr_build<<<NBu, 256, 0, stream>>>(pairs, A, csr_ptr, csr_src, N, NBu);
  k_gemm1<<<(N + 63) / 64, 256, 0, stream>>>(x, W1l, W1r, xl1, xr1, N);
  k_edge1<<<(N + 255) / 256, 256, 0, stream>>>(csr_ptr, csr_src, xl1, xr1, a1, b1,
                                               W2l, W2r, xl2, xr2, N);
  k_edge2<<<(N + 255) / 256, 256, 0, stream>>>(csr_ptr, csr_src, xl2, xr2, a2, b2, h2, N);
  k_pool_final<<<G, 256, 0, stream>>>(h2, batch, Wlin, blin, out, N);
}

// Round 6
// 202.069 us; speedup vs baseline: 1.1956x; 1.1956x over previous
//
#include <hip/hip_runtime.h>
#include <hip/hip_bf16.h>
#include <math.h>

#define NBLK 256   // binning blocks
#define NBS  512   // bucket slots (pow2 bucket = 256 nodes => 391 used)

// ---------------- binned CSR build (no global atomics, pow2 buckets) ----------------
__global__ __launch_bounds__(256) void k_bin_count(const int* __restrict__ ei,
    int E, int ET, int chunk, int* __restrict__ A) {
  __shared__ int lh[NBS];
  int t = threadIdx.x;
  lh[t] = 0; lh[t + 256] = 0;
  __syncthreads();
  int beg = blockIdx.x * chunk, end = min(beg + chunk, ET);
  for (int i = beg + t; i < end; i += 256) {
    int d = (i < E) ? ei[E + i] : (i - E);      // self loop for i>=E
    atomicAdd(&lh[d >> 8], 1);
  }
  __syncthreads();
  A[t * NBLK + blockIdx.x] = lh[t];
  A[(t + 256) * NBLK + blockIdx.x] = lh[t + 256];
}

__global__ void k_reduce(const int* __restrict__ a, int* bsum, int n) {
  int i = blockIdx.x * 256 + threadIdx.x;
  int v = (i < n) ? a[i] : 0;
  #pragma unroll
  for (int off = 32; off; off >>= 1) v += __shfl_down(v, off, 64);
  __shared__ int sh[4];
  if ((threadIdx.x & 63) == 0) sh[threadIdx.x >> 6] = v;
  __syncthreads();
  if (threadIdx.x == 0) bsum[blockIdx.x] = sh[0] + sh[1] + sh[2] + sh[3];
}

__global__ void k_scan_bsum(int* bsum, int nb) {
  __shared__ int sh[512];
  int t = threadIdx.x;
  int v = (t < nb) ? bsum[t] : 0;
  sh[t] = v; __syncthreads();
  for (int off = 1; off < 512; off <<= 1) {
    int add = (t >= off) ? sh[t - off] : 0;
    __syncthreads();
    sh[t] += add;
    __syncthreads();
  }
  if (t < nb) bsum[t] = sh[t] - v;   // exclusive
}

__global__ void k_scan_apply(int* A, const int* __restrict__ bsum, int n) {
  __shared__ int sh[256];
  int t = threadIdx.x; int i = blockIdx.x * 256 + t;
  int v = (i < n) ? A[i] : 0;
  sh[t] = v; __syncthreads();
  for (int off = 1; off < 256; off <<= 1) {
    int add = (t >= off) ? sh[t - off] : 0;
    __syncthreads();
    sh[t] += add;
    __syncthreads();
  }
  int excl = sh[t] - v + bsum[blockIdx.x];
  if (i < n) A[i] = excl;
  if (i == n - 1) A[n] = excl + v;
}

__global__ __launch_bounds__(256) void k_bin_scatter(const int* __restrict__ ei,
    int E, int ET, int chunk, const int* __restrict__ A, int* __restrict__ pairs) {
  __shared__ int cur[NBS];
  int t = threadIdx.x;
  cur[t]       = A[t * NBLK + blockIdx.x];
  cur[t + 256] = A[(t + 256) * NBLK + blockIdx.x];
  __syncthreads();
  int beg = blockIdx.x * chunk, end = min(beg + chunk, ET);
  for (int i = beg + t; i < end; i += 256) {
    int s, d;
    if (i < E) { s = ei[i]; d = ei[E + i]; } else { s = d = i - E; }
    int pos = atomicAdd(&cur[d >> 8], 1);
    pairs[pos] = (s << 8) | (d & 255);        // src<2^24, local dst in 8 bits
  }
}

__global__ __launch_bounds__(256) void k_csr_build(const int* __restrict__ pairs,
    const int* __restrict__ A, int* __restrict__ csr_ptr, int* __restrict__ csr_src,
    int N, int NBu) {
  __shared__ int cnt[256];
  __shared__ int cur[256];
  __shared__ int sh[256];
  int b = blockIdx.x, t = threadIdx.x;
  int base = A[b * NBLK], endp = A[(b + 1) * NBLK];
  int node0 = b << 8;
  cnt[t] = 0;
  __syncthreads();
  for (int e = base + t; e < endp; e += 256)
    atomicAdd(&cnt[pairs[e] & 255], 1);
  __syncthreads();
  int v = cnt[t];
  sh[t] = v; __syncthreads();
  for (int off = 1; off < 256; off <<= 1) {
    int add = (t >= off) ? sh[t - off] : 0;
    __syncthreads();
    sh[t] += add;
    __syncthreads();
  }
  int excl = sh[t] - v;
  if (node0 + t < N) csr_ptr[node0 + t] = base + excl;
  cur[t] = base + excl;
  if (b == NBu - 1 && t == 0) csr_ptr[N] = endp;
  __syncthreads();
  for (int e = base + t; e < endp; e += 256) {
    int p = pairs[e];
    int pos = atomicAdd(&cur[p & 255], 1);
    csr_src[pos] = ((unsigned)p) >> 8;
  }
}

// ---------------- layer 1 transform: xl1 = x@W1l, xr1 = x@W1r ----------------
__global__ __launch_bounds__(256) void k_gemm1(const float* __restrict__ x,
    const float* __restrict__ Wl, const float* __restrict__ Wr,
    float* __restrict__ xl, float* __restrict__ xr, int n) {
  __shared__ float xs[64 * 132];
  __shared__ float Ws[128 * 32];
  int t = threadIdx.x;
  int r0 = blockIdx.x * 64;
  #pragma unroll
  for (int i = 0; i < 8; i++) {
    int idx = t + i * 256;
    int k = idx >> 4, c = idx & 15;
    Ws[k * 32 + c]      = Wl[idx];
    Ws[k * 32 + 16 + c] = Wr[idx];
  }
  #pragma unroll
  for (int i = 0; i < 8; i++) {
    int v = t + i * 256;
    int row = v >> 5;
    int col4 = v & 31;
    float4 val = make_float4(0.f, 0.f, 0.f, 0.f);
    if (r0 + row < n)
      val = reinterpret_cast<const float4*>(x)[(long)(r0 + row) * 32 + col4];
    float* dst = &xs[row * 132 + col4 * 4];
    dst[0] = val.x; dst[1] = val.y; dst[2] = val.z; dst[3] = val.w;
  }
  __syncthreads();
  int g = t >> 2;
  int sub = t & 3;
  float acc[8] = {0.f,0.f,0.f,0.f,0.f,0.f,0.f,0.f};
  #pragma unroll 4
  for (int k = 0; k < 128; k++) {
    float xv = xs[g * 132 + k];
    const float4* wp = reinterpret_cast<const float4*>(&Ws[k * 32 + sub * 8]);
    float4 w0 = wp[0], w1 = wp[1];
    acc[0] += xv * w0.x; acc[1] += xv * w0.y; acc[2] += xv * w0.z; acc[3] += xv * w0.w;
    acc[4] += xv * w1.x; acc[5] += xv * w1.y; acc[6] += xv * w1.z; acc[7] += xv * w1.w;
  }
  int row = r0 + g;
  if (row < n) {
    float* o = (sub < 2) ? &xl[(long)row * 16 + sub * 8]
                         : &xr[(long)row * 16 + (sub - 2) * 8];
    float4* o4 = reinterpret_cast<float4*>(o);
    o4[0] = make_float4(acc[0], acc[1], acc[2], acc[3]);
    o4[1] = make_float4(acc[4], acc[5], acc[6], acc[7]);
  }
}

// ---------------- quad DPP helpers (cross-lane within quad, VALU only) ----------------
template<int CTRL>
__device__ __forceinline__ float dpp_mov(float x) {
  return __int_as_float(__builtin_amdgcn_update_dpp(0, __float_as_int(x), CTRL, 0xF, 0xF, true));
}
__device__ __forceinline__ float quad_sum(float x) {
  x += dpp_mov<0xB1>(x);   // xor 1
  x += dpp_mov<0x4E>(x);   // xor 2
  return x;
}
__device__ __forceinline__ float quad_max(float x) {
  x = fmaxf(x, dpp_mov<0xB1>(x));
  x = fmaxf(x, dpp_mov<0x4E>(x));
  return x;
}

// ------- layer-1 edge aggregation: 4 lanes/node, channels in regs, fused gemm2 -------
// leaky(z) = 0.6z + 0.4|z| (slope 0.2). Defer-max: m=0 unless e>m+25 (exact fallback).
__global__ __launch_bounds__(256) void k_edge1(const int* __restrict__ csr_ptr,
    const int* __restrict__ csr_src, const float* __restrict__ xl,
    const float* __restrict__ xr, const float* __restrict__ att,
    const float* __restrict__ bias, const float* __restrict__ W2l,
    const float* __restrict__ W2r, float* __restrict__ xl2,
    float* __restrict__ xr2, int n) {
  __shared__ float Ws[16 * 16];    // [k][j]: j<8 -> W2l, j>=8 -> W2r
  int t = threadIdx.x;
  if (t < 128) {
    int k = t >> 3, j = t & 7;
    Ws[k * 16 + j]     = W2l[t];
    Ws[k * 16 + 8 + j] = W2r[t];
  }
  __syncthreads();
  int node = blockIdx.x * 64 + (t >> 2);
  int sub = t & 3;
  if (node >= n) return;
  int beg = csr_ptr[node], end = csr_ptr[node + 1];
  float xrv[16], av[16], nu[16];
  const float4* xrp = reinterpret_cast<const float4*>(xr + (long)node * 16);
  #pragma unroll
  for (int q = 0; q < 4; q++) {
    float4 v = xrp[q];
    xrv[q*4] = v.x; xrv[q*4+1] = v.y; xrv[q*4+2] = v.z; xrv[q*4+3] = v.w;
  }
  #pragma unroll
  for (int c = 0; c < 16; c++) { av[c] = att[c]; nu[c] = 0.f; }
  float m = 0.f, s = 0.f;
  for (int i = beg + sub; i < end; i += 4) {
    int src = csr_src[i];
    float xlv[16];
    const float4* p = reinterpret_cast<const float4*>(xl + (long)src * 16);
    #pragma unroll
    for (int q = 0; q < 4; q++) {
      float4 v = p[q];
      xlv[q*4] = v.x; xlv[q*4+1] = v.y; xlv[q*4+2] = v.z; xlv[q*4+3] = v.w;
    }
    float e1a = 0.f, e1b = 0.f, e2a = 0.f, e2b = 0.f;
    #pragma unroll
    for (int c = 0; c < 8; c++) {
      float za = xlv[c] + xrv[c];
      float zb = xlv[c + 8] + xrv[c + 8];
      e1a += av[c] * za;       e2a += av[c] * fabsf(za);
      e1b += av[c + 8] * zb;   e2b += av[c + 8] * fabsf(zb);
    }
    float e = 0.6f * (e1a + e1b) + 0.4f * (e2a + e2b);
    if (e > m + 25.f) {                       // rare exact rescale fallback
      float sc = __expf(m - e);
      s *= sc;
      #pragma unroll
      for (int c = 0; c < 16; c++) nu[c] *= sc;
      m = e;
    }
    float pe = __expf(e - m);
    s += pe;
    #pragma unroll
    for (int c = 0; c < 16; c++) nu[c] += pe * xlv[c];
  }
  // merge the 4 per-lane chains within the quad (exact)
  float M = quad_max(m);
  float sc = __expf(m - M);
  float S = quad_sum(s * sc);
  float o[16];
  #pragma unroll
  for (int c = 0; c < 16; c++) o[c] = quad_sum(nu[c] * sc);
  float inv = 1.f / fmaxf(S, 1e-16f);
  #pragma unroll
  for (int c = 0; c < 16; c++) o[c] = fmaxf(o[c] * inv + bias[c], 0.f);  // relu(h1)
  // fused layer-2 transform: this lane computes its 4 output channels only.
  // sub0: xl2[0..3], sub1: xl2[4..7], sub2: xr2[0..3], sub3: xr2[4..7]
  float r[4] = {0.f, 0.f, 0.f, 0.f};
  int j0 = sub * 4;
  #pragma unroll
  for (int k = 0; k < 16; k++) {
    float ok = o[k];
    const float* wk = &Ws[k * 16 + j0];
    r[0] += ok * wk[0]; r[1] += ok * wk[1]; r[2] += ok * wk[2]; r[3] += ok * wk[3];
  }
  float* dst = (sub < 2) ? (xl2 + (long)node * 8 + (sub & 1) * 4)
                         : (xr2 + (long)node * 8 + (sub & 1) * 4);
  *reinterpret_cast<float4*>(dst) = make_float4(r[0], r[1], r[2], r[3]);
}

// ------- layer-2 edge aggregation: 4 lanes/node -------
__global__ __launch_bounds__(256) void k_edge2(const int* __restrict__ csr_ptr,
    const int* __restrict__ csr_src, const float* __restrict__ xl,
    const float* __restrict__ xr, const float* __restrict__ att,
    const float* __restrict__ bias, float* __restrict__ out, int n) {
  int t = threadIdx.x;
  int node = blockIdx.x * 64 + (t >> 2);
  int sub = t & 3;
  if (node >= n) return;
  int beg = csr_ptr[node], end = csr_ptr[node + 1];
  float xrv[8], av[8], nu[8];
  const float4* xrp = reinterpret_cast<const float4*>(xr + (long)node * 8);
  {
    float4 v0 = xrp[0], v1 = xrp[1];
    xrv[0]=v0.x; xrv[1]=v0.y; xrv[2]=v0.z; xrv[3]=v0.w;
    xrv[4]=v1.x; xrv[5]=v1.y; xrv[6]=v1.z; xrv[7]=v1.w;
  }
  #pragma unroll
  for (int c = 0; c < 8; c++) { av[c] = att[c]; nu[c] = 0.f; }
  float m = 0.f, s = 0.f;
  for (int i = beg + sub; i < end; i += 4) {
    int src = csr_src[i];
    float xlv[8];
    const float4* p = reinterpret_cast<const float4*>(xl + (long)src * 8);
    float4 v0 = p[0], v1 = p[1];
    xlv[0]=v0.x; xlv[1]=v0.y; xlv[2]=v0.z; xlv[3]=v0.w;
    xlv[4]=v1.x; xlv[5]=v1.y; xlv[6]=v1.z; xlv[7]=v1.w;
    float e1a = 0.f, e1b = 0.f, e2a = 0.f, e2b = 0.f;
    #pragma unroll
    for (int c = 0; c < 4; c++) {
      float za = xlv[c] + xrv[c];
      float zb = xlv[c + 4] + xrv[c + 4];
      e1a += av[c] * za;       e2a += av[c] * fabsf(za);
      e1b += av[c + 4] * zb;   e2b += av[c + 4] * fabsf(zb);
    }
    float e = 0.6f * (e1a + e1b) + 0.4f * (e2a + e2b);
    if (e > m + 25.f) {
      float sc = __expf(m - e);
      s *= sc;
      #pragma unroll
      for (int c = 0; c < 8; c++) nu[c] *= sc;
      m = e;
    }
    float pe = __expf(e - m);
    s += pe;
    #pragma unroll
    for (int c = 0; c < 8; c++) nu[c] += pe * xlv[c];
  }
  float M = quad_max(m);
  float sc = __expf(m - M);
  float S = quad_sum(s * sc);
  float o[8];
  #pragma unroll
  for (int c = 0; c < 8; c++) o[c] = quad_sum(nu[c] * sc);
  float inv = 1.f / fmaxf(S, 1e-16f);
  #pragma unroll
  for (int c = 0; c < 8; c++) o[c] = fmaxf(o[c] * inv + bias[c], 0.f);
  if (sub < 2) {
    float4* po = reinterpret_cast<float4*>(out + (long)node * 8 + sub * 4);
    *po = make_float4(o[sub*4], o[sub*4+1], o[sub*4+2], o[sub*4+3]);
  }
}

// ---------------- fused mean pool + linear: one block per graph ----------------
__global__ __launch_bounds__(256) void k_pool_final(const float* __restrict__ h,
    const int* __restrict__ batch, const float* __restrict__ Wlin,
    const float* __restrict__ blin, float* __restrict__ out, int n) {
  int g = blockIdx.x;
  int lo = 0, hi = n;
  while (lo < hi) { int mid = (lo + hi) >> 1; if (batch[mid] < g) lo = mid + 1; else hi = mid; }
  int beg = lo;
  hi = n;
  while (lo < hi) { int mid = (lo + hi) >> 1; if (batch[mid] < g + 1) lo = mid + 1; else hi = mid; }
  int end = lo;

  float w[8];
  #pragma unroll
  for (int c = 0; c < 8; c++) w[c] = Wlin[c];

  float acc = 0.f;
  int t = threadIdx.x;
  for (int i = beg + t; i < end; i += 256) {
    const float4* hp = reinterpret_cast<const float4*>(h + (long)i * 8);
    float4 v0 = hp[0], v1 = hp[1];
    acc += v0.x * w[0] + v0.y * w[1] + v0.z * w[2] + v0.w * w[3]
         + v1.x * w[4] + v1.y * w[5] + v1.z * w[6] + v1.w * w[7];
  }
  #pragma unroll
  for (int off = 32; off; off >>= 1) acc += __shfl_down(acc, off, 64);
  __shared__ float sh[4];
  if ((t & 63) == 0) sh[t >> 6] = acc;
  __syncthreads();
  if (t == 0) {
    float total = sh[0] + sh[1] + sh[2] + sh[3];
    float cnt = (float)(end - beg);
    out[g] = total / fmaxf(cnt, 1.f) + blin[0];
  }
}

extern "C" void kernel_launch(void* const* d_in, const int* in_sizes, int n_in,
                              void* d_out, int out_size, void* d_ws, size_t ws_size,
                              hipStream_t stream) {
  (void)n_in; (void)ws_size;
  const float* x    = (const float*)d_in[0];
  const int*   ei   = (const int*)d_in[1];
  const int*   batch= (const int*)d_in[2];
  const float* W1l  = (const float*)d_in[3];
  const float* W1r  = (const float*)d_in[4];
  const float* a1   = (const float*)d_in[5];
  const float* b1   = (const float*)d_in[6];
  const float* W2l  = (const float*)d_in[7];
  const float* W2r  = (const float*)d_in[8];
  const float* a2   = (const float*)d_in[9];
  const float* b2   = (const float*)d_in[10];
  const float* Wlin = (const float*)d_in[11];
  const float* blin = (const float*)d_in[12];
  float* out = (float*)d_out;

  int N = in_sizes[0] / 128;
  int E = in_sizes[1] / 2;
  int G = out_size;                 // 256 graphs
  int ET = E + N;                   // edges incl self loops
  int NBu = (N + 255) >> 8;         // used buckets (256 nodes each), <= NBS
  int chunk = (ET + NBLK - 1) / NBLK;
  int nA = NBS * NBLK;              // 131072

  char* ws = (char*)d_ws;
  size_t off = 0;
  auto alloc = [&](size_t bytes) {
    void* p = ws + off; off = (off + bytes + 255) & ~(size_t)255; return p;
  };
  int* csr_ptr = (int*)alloc((size_t)(N + 1) * 4);
  int* A       = (int*)alloc((size_t)(nA + 1) * 4);
  int* bsum    = (int*)alloc(512 * 4);
  int* csr_src = (int*)alloc((size_t)ET * 4);
  // union: packed pairs (ET*4 B) time-shared with feature buffers (N*224 B)
  size_t featBytes = (size_t)N * (16 + 16 + 8 + 8 + 8) * 4;
  size_t pairBytes = (size_t)ET * 4;
  char* u = (char*)alloc(pairBytes > featBytes ? pairBytes : featBytes);
  int* pairs = (int*)u;
  float* xl1 = (float*)u;
  float* xr1 = xl1 + (size_t)N * 16;
  float* xl2 = xr1 + (size_t)N * 16;
  float* xr2 = xl2 + (size_t)N * 8;
  float* h2  = xr2 + (size_t)N * 8;

  k_bin_count<<<NBLK, 256, 0, stream>>>(ei, E, ET, chunk, A);
  k_reduce<<<(nA + 255) / 256, 256, 0, stream>>>(A, bsum, nA);
  k_scan_bsum<<<1, 512, 0, stream>>>(bsum, (nA + 255) / 256);
  k_scan_apply<<<(nA + 255) / 256, 256, 0, stream>>>(A, bsum, nA);
  k_bin_scatter<<<NBLK, 256, 0, stream>>>(ei, E, ET, chunk, A, pairs);
  k_csr_build<<<NBu, 256, 0, stream>>>(pairs, A, csr_ptr, csr_src, N, NBu);
  k_gemm1<<<(N + 63) / 64, 256, 0, stream>>>(x, W1l, W1r, xl1, xr1, N);
  k_edge1<<<(N + 63) / 64, 256, 0, stream>>>(csr_ptr, csr_src, xl1, xr1, a1, b1,
                                             W2l, W2r, xl2, xr2, N);
  k_edge2<<<(N + 63) / 64, 256, 0, stream>>>(csr_ptr, csr_src, xl2, xr2, a2, b2, h2, N);
  k_pool_final<<<G, 256, 0, stream>>>(h2, batch, Wlin, blin, out, N);
}

// Round 7
// 181.749 us; speedup vs baseline: 1.3293x; 1.1118x over previous
//
#include <hip/hip_runtime.h>
#include <hip/hip_bf16.h>
#include <math.h>

#define NBLK 256   // binning blocks
#define NBS  512   // bucket slots (pow2 bucket = 256 nodes => 391 used)

// ---------------- bf16 helpers (RNE) ----------------
__device__ __forceinline__ unsigned bfr(float x) {      // f32 -> bf16 bits (RNE)
  unsigned u = __float_as_uint(x);
  return (u + 0x7fffu + ((u >> 16) & 1u)) >> 16;
}
__device__ __forceinline__ unsigned bfpk(float lo, float hi) {
  return (bfr(hi) << 16) | bfr(lo);
}
__device__ __forceinline__ float bflo(unsigned u) { return __uint_as_float(u << 16); }
__device__ __forceinline__ float bfhi(unsigned u) { return __uint_as_float(u & 0xffff0000u); }

// ---------------- binned CSR build (no global atomics, pow2 buckets) ----------------
__global__ __launch_bounds__(256) void k_bin_count(const int* __restrict__ ei,
    int E, int ET, int chunk, int* __restrict__ A) {
  __shared__ int lh[NBS];
  int t = threadIdx.x;
  lh[t] = 0; lh[t + 256] = 0;
  __syncthreads();
  int beg = blockIdx.x * chunk, end = min(beg + chunk, ET);
  for (int i = beg + t; i < end; i += 256) {
    int d = (i < E) ? ei[E + i] : (i - E);      // self loop for i>=E
    atomicAdd(&lh[d >> 8], 1);
  }
  __syncthreads();
  A[t * NBLK + blockIdx.x] = lh[t];
  A[(t + 256) * NBLK + blockIdx.x] = lh[t + 256];
}

__global__ void k_reduce(const int* __restrict__ a, int* bsum, int n) {
  int i = blockIdx.x * 256 + threadIdx.x;
  int v = (i < n) ? a[i] : 0;
  #pragma unroll
  for (int off = 32; off; off >>= 1) v += __shfl_down(v, off, 64);
  __shared__ int sh[4];
  if ((threadIdx.x & 63) == 0) sh[threadIdx.x >> 6] = v;
  __syncthreads();
  if (threadIdx.x == 0) bsum[blockIdx.x] = sh[0] + sh[1] + sh[2] + sh[3];
}

__global__ void k_scan_bsum(int* bsum, int nb) {
  __shared__ int sh[512];
  int t = threadIdx.x;
  int v = (t < nb) ? bsum[t] : 0;
  sh[t] = v; __syncthreads();
  for (int off = 1; off < 512; off <<= 1) {
    int add = (t >= off) ? sh[t - off] : 0;
    __syncthreads();
    sh[t] += add;
    __syncthreads();
  }
  if (t < nb) bsum[t] = sh[t] - v;   // exclusive
}

__global__ void k_scan_apply(int* A, const int* __restrict__ bsum, int n) {
  __shared__ int sh[256];
  int t = threadIdx.x; int i = blockIdx.x * 256 + t;
  int v = (i < n) ? A[i] : 0;
  sh[t] = v; __syncthreads();
  for (int off = 1; off < 256; off <<= 1) {
    int add = (t >= off) ? sh[t - off] : 0;
    __syncthreads();
    sh[t] += add;
    __syncthreads();
  }
  int excl = sh[t] - v + bsum[blockIdx.x];
  if (i < n) A[i] = excl;
  if (i == n - 1) A[n] = excl + v;
}

__global__ __launch_bounds__(256) void k_bin_scatter(const int* __restrict__ ei,
    int E, int ET, int chunk, const int* __restrict__ A, int* __restrict__ pairs) {
  __shared__ int cur[NBS];
  int t = threadIdx.x;
  cur[t]       = A[t * NBLK + blockIdx.x];
  cur[t + 256] = A[(t + 256) * NBLK + blockIdx.x];
  __syncthreads();
  int beg = blockIdx.x * chunk, end = min(beg + chunk, ET);
  for (int i = beg + t; i < end; i += 256) {
    int s, d;
    if (i < E) { s = ei[i]; d = ei[E + i]; } else { s = d = i - E; }
    int pos = atomicAdd(&cur[d >> 8], 1);
    pairs[pos] = (s << 8) | (d & 255);        // src<2^24, local dst in 8 bits
  }
}

__global__ __launch_bounds__(256) void k_csr_build(const int* __restrict__ pairs,
    const int* __restrict__ A, int* __restrict__ csr_ptr, int* __restrict__ csr_src,
    int N, int NBu) {
  __shared__ int cnt[256];
  __shared__ int cur[256];
  __shared__ int sh[256];
  int b = blockIdx.x, t = threadIdx.x;
  int base = A[b * NBLK], endp = A[(b + 1) * NBLK];
  int node0 = b << 8;
  cnt[t] = 0;
  __syncthreads();
  for (int e = base + t; e < endp; e += 256)
    atomicAdd(&cnt[pairs[e] & 255], 1);
  __syncthreads();
  int v = cnt[t];
  sh[t] = v; __syncthreads();
  for (int off = 1; off < 256; off <<= 1) {
    int add = (t >= off) ? sh[t - off] : 0;
    __syncthreads();
    sh[t] += add;
    __syncthreads();
  }
  int excl = sh[t] - v;
  if (node0 + t < N) csr_ptr[node0 + t] = base + excl;
  cur[t] = base + excl;
  if (b == NBu - 1 && t == 0) csr_ptr[N] = endp;
  __syncthreads();
  for (int e = base + t; e < endp; e += 256) {
    int p = pairs[e];
    int pos = atomicAdd(&cur[p & 255], 1);
    csr_src[pos] = ((unsigned)p) >> 8;
  }
}

// ----- layer 1 transform: xl1(bf16) = x@W1l, xr1(f32) = x@W1r -----
__global__ __launch_bounds__(256) void k_gemm1(const float* __restrict__ x,
    const float* __restrict__ Wl, const float* __restrict__ Wr,
    unsigned* __restrict__ xlb, float* __restrict__ xr, int n) {
  __shared__ float xs[64 * 132];
  __shared__ float Ws[128 * 32];
  int t = threadIdx.x;
  int r0 = blockIdx.x * 64;
  #pragma unroll
  for (int i = 0; i < 8; i++) {
    int idx = t + i * 256;
    int k = idx >> 4, c = idx & 15;
    Ws[k * 32 + c]      = Wl[idx];
    Ws[k * 32 + 16 + c] = Wr[idx];
  }
  #pragma unroll
  for (int i = 0; i < 8; i++) {
    int v = t + i * 256;
    int row = v >> 5;
    int col4 = v & 31;
    float4 val = make_float4(0.f, 0.f, 0.f, 0.f);
    if (r0 + row < n)
      val = reinterpret_cast<const float4*>(x)[(long)(r0 + row) * 32 + col4];
    float* dst = &xs[row * 132 + col4 * 4];
    dst[0] = val.x; dst[1] = val.y; dst[2] = val.z; dst[3] = val.w;
  }
  __syncthreads();
  int g = t >> 2;
  int sub = t & 3;
  float acc[8] = {0.f,0.f,0.f,0.f,0.f,0.f,0.f,0.f};
  #pragma unroll 4
  for (int k = 0; k < 128; k++) {
    float xv = xs[g * 132 + k];
    const float4* wp = reinterpret_cast<const float4*>(&Ws[k * 32 + sub * 8]);
    float4 w0 = wp[0], w1 = wp[1];
    acc[0] += xv * w0.x; acc[1] += xv * w0.y; acc[2] += xv * w0.z; acc[3] += xv * w0.w;
    acc[4] += xv * w1.x; acc[5] += xv * w1.y; acc[6] += xv * w1.z; acc[7] += xv * w1.w;
  }
  int row = r0 + g;
  if (row < n) {
    if (sub < 2) {       // xl channels sub*8 .. sub*8+7 as bf16 (4 uints = 16 B)
      uint4 pk;
      pk.x = bfpk(acc[0], acc[1]); pk.y = bfpk(acc[2], acc[3]);
      pk.z = bfpk(acc[4], acc[5]); pk.w = bfpk(acc[6], acc[7]);
      reinterpret_cast<uint4*>(xlb)[(long)row * 2 + sub] = pk;
    } else {             // xr channels (sub-2)*8 .. +7 as f32
      float4* o4 = reinterpret_cast<float4*>(&xr[(long)row * 16 + (sub - 2) * 8]);
      o4[0] = make_float4(acc[0], acc[1], acc[2], acc[3]);
      o4[1] = make_float4(acc[4], acc[5], acc[6], acc[7]);
    }
  }
}

// ---------------- quad DPP helpers (cross-lane within quad, VALU only) ----------------
template<int CTRL>
__device__ __forceinline__ float dpp_mov(float x) {
  return __int_as_float(__builtin_amdgcn_update_dpp(0, __float_as_int(x), CTRL, 0xF, 0xF, true));
}
__device__ __forceinline__ float quad_sum(float x) {
  x += dpp_mov<0xB1>(x);   // xor 1
  x += dpp_mov<0x4E>(x);   // xor 2
  return x;
}
__device__ __forceinline__ float quad_max(float x) {
  x = fmaxf(x, dpp_mov<0xB1>(x));
  x = fmaxf(x, dpp_mov<0x4E>(x));
  return x;
}

// ------- layer-1 edge aggregation: 4 lanes/node, bf16 gather, prefetch, fused gemm2 -------
// leaky(z) = 0.6z + 0.4|z| (slope 0.2). Defer-max: m=0 unless e>m+25 (exact fallback).
__global__ __launch_bounds__(256) void k_edge1(const int* __restrict__ csr_ptr,
    const int* __restrict__ csr_src, const unsigned* __restrict__ xlb,
    const float* __restrict__ xr, const float* __restrict__ att,
    const float* __restrict__ bias, const float* __restrict__ W2l,
    const float* __restrict__ W2r, unsigned* __restrict__ xl2b,
    float* __restrict__ xr2, int n) {
  __shared__ float Ws[16 * 16];    // [k][j]: j<8 -> W2l, j>=8 -> W2r
  int t = threadIdx.x;
  if (t < 128) {
    int k = t >> 3, j = t & 7;
    Ws[k * 16 + j]     = W2l[t];
    Ws[k * 16 + 8 + j] = W2r[t];
  }
  __syncthreads();
  int node = blockIdx.x * 64 + (t >> 2);
  int sub = t & 3;
  if (node >= n) return;
  int beg = csr_ptr[node], end = csr_ptr[node + 1];
  float xrv[16], av[16], nu[16];
  const float4* xrp = reinterpret_cast<const float4*>(xr + (long)node * 16);
  #pragma unroll
  for (int q = 0; q < 4; q++) {
    float4 v = xrp[q];
    xrv[q*4] = v.x; xrv[q*4+1] = v.y; xrv[q*4+2] = v.z; xrv[q*4+3] = v.w;
  }
  #pragma unroll
  for (int c = 0; c < 16; c++) { av[c] = att[c]; nu[c] = 0.f; }
  float m = 0.f, s = 0.f;
  int i = beg + sub;
  uint4 ra, rb;
  if (i < end) {
    const uint4* p = reinterpret_cast<const uint4*>(xlb + (long)csr_src[i] * 8);
    ra = p[0]; rb = p[1];
  }
  while (i < end) {
    int nx = i + 4;
    uint4 na = ra, nb = rb;
    if (nx < end) {
      const uint4* p = reinterpret_cast<const uint4*>(xlb + (long)csr_src[nx] * 8);
      na = p[0]; nb = p[1];
    }
    unsigned uu[8] = {ra.x, ra.y, ra.z, ra.w, rb.x, rb.y, rb.z, rb.w};
    float xlv[16];
    #pragma unroll
    for (int k = 0; k < 8; k++) { xlv[2*k] = bflo(uu[k]); xlv[2*k+1] = bfhi(uu[k]); }
    float e1a = 0.f, e1b = 0.f, e2a = 0.f, e2b = 0.f;
    #pragma unroll
    for (int c = 0; c < 8; c++) {
      float za = xlv[c] + xrv[c];
      float zb = xlv[c + 8] + xrv[c + 8];
      e1a += av[c] * za;       e2a += av[c] * fabsf(za);
      e1b += av[c + 8] * zb;   e2b += av[c + 8] * fabsf(zb);
    }
    float e = 0.6f * (e1a + e1b) + 0.4f * (e2a + e2b);
    if (e > m + 25.f) {                       // rare exact rescale fallback
      float sc = __expf(m - e);
      s *= sc;
      #pragma unroll
      for (int c = 0; c < 16; c++) nu[c] *= sc;
      m = e;
    }
    float pe = __expf(e - m);
    s += pe;
    #pragma unroll
    for (int c = 0; c < 16; c++) nu[c] += pe * xlv[c];
    ra = na; rb = nb; i = nx;
  }
  // merge the 4 per-lane chains within the quad (exact)
  float M = quad_max(m);
  float sc = __expf(m - M);
  float S = quad_sum(s * sc);
  float o[16];
  #pragma unroll
  for (int c = 0; c < 16; c++) o[c] = quad_sum(nu[c] * sc);
  float inv = 1.f / fmaxf(S, 1e-16f);
  #pragma unroll
  for (int c = 0; c < 16; c++) o[c] = fmaxf(o[c] * inv + bias[c], 0.f);  // relu(h1)
  // fused layer-2 transform: this lane computes its 4 output channels.
  // sub0: xl2[0..3], sub1: xl2[4..7], sub2: xr2[0..3], sub3: xr2[4..7]
  float r[4] = {0.f, 0.f, 0.f, 0.f};
  int j0 = sub * 4;
  #pragma unroll
  for (int k = 0; k < 16; k++) {
    float ok = o[k];
    const float* wk = &Ws[k * 16 + j0];
    r[0] += ok * wk[0]; r[1] += ok * wk[1]; r[2] += ok * wk[2]; r[3] += ok * wk[3];
  }
  if (sub < 2) {   // xl2 bf16: 4 vals -> uint2 (8 B)
    uint2 pk; pk.x = bfpk(r[0], r[1]); pk.y = bfpk(r[2], r[3]);
    reinterpret_cast<uint2*>(xl2b)[(long)node * 2 + sub] = pk;
  } else {         // xr2 f32
    reinterpret_cast<float4*>(xr2)[(long)node * 2 + (sub - 2)] =
        make_float4(r[0], r[1], r[2], r[3]);
  }
}

// ------- layer-2 edge aggregation: 4 lanes/node, bf16 gather, prefetch -------
__global__ __launch_bounds__(256) void k_edge2(const int* __restrict__ csr_ptr,
    const int* __restrict__ csr_src, const unsigned* __restrict__ xlb,
    const float* __restrict__ xr, const float* __restrict__ att,
    const float* __restrict__ bias, float* __restrict__ out, int n) {
  int t = threadIdx.x;
  int node = blockIdx.x * 64 + (t >> 2);
  int sub = t & 3;
  if (node >= n) return;
  int beg = csr_ptr[node], end = csr_ptr[node + 1];
  float xrv[8], av[8], nu[8];
  const float4* xrp = reinterpret_cast<const float4*>(xr + (long)node * 8);
  {
    float4 v0 = xrp[0], v1 = xrp[1];
    xrv[0]=v0.x; xrv[1]=v0.y; xrv[2]=v0.z; xrv[3]=v0.w;
    xrv[4]=v1.x; xrv[5]=v1.y; xrv[6]=v1.z; xrv[7]=v1.w;
  }
  #pragma unroll
  for (int c = 0; c < 8; c++) { av[c] = att[c]; nu[c] = 0.f; }
  float m = 0.f, s = 0.f;
  int i = beg + sub;
  uint4 ra;
  if (i < end) ra = reinterpret_cast<const uint4*>(xlb)[csr_src[i]];
  while (i < end) {
    int nx = i + 4;
    uint4 na = ra;
    if (nx < end) na = reinterpret_cast<const uint4*>(xlb)[csr_src[nx]];
    unsigned uu[4] = {ra.x, ra.y, ra.z, ra.w};
    float xlv[8];
    #pragma unroll
    for (int k = 0; k < 4; k++) { xlv[2*k] = bflo(uu[k]); xlv[2*k+1] = bfhi(uu[k]); }
    float e1a = 0.f, e1b = 0.f, e2a = 0.f, e2b = 0.f;
    #pragma unroll
    for (int c = 0; c < 4; c++) {
      float za = xlv[c] + xrv[c];
      float zb = xlv[c + 4] + xrv[c + 4];
      e1a += av[c] * za;       e2a += av[c] * fabsf(za);
      e1b += av[c + 4] * zb;   e2b += av[c + 4] * fabsf(zb);
    }
    float e = 0.6f * (e1a + e1b) + 0.4f * (e2a + e2b);
    if (e > m + 25.f) {
      float sc = __expf(m - e);
      s *= sc;
      #pragma unroll
      for (int c = 0; c < 8; c++) nu[c] *= sc;
      m = e;
    }
    float pe = __expf(e - m);
    s += pe;
    #pragma unroll
    for (int c = 0; c < 8; c++) nu[c] += pe * xlv[c];
    ra = na; i = nx;
  }
  float M = quad_max(m);
  float sc = __expf(m - M);
  float S = quad_sum(s * sc);
  float o[8];
  #pragma unroll
  for (int c = 0; c < 8; c++) o[c] = quad_sum(nu[c] * sc);
  float inv = 1.f / fmaxf(S, 1e-16f);
  #pragma unroll
  for (int c = 0; c < 8; c++) o[c] = fmaxf(o[c] * inv + bias[c], 0.f);
  if (sub < 2) {
    float4* po = reinterpret_cast<float4*>(out + (long)node * 8 + sub * 4);
    *po = make_float4(o[sub*4], o[sub*4+1], o[sub*4+2], o[sub*4+3]);
  }
}

// ---------------- fused mean pool + linear: one block per graph ----------------
__global__ __launch_bounds__(256) void k_pool_final(const float* __restrict__ h,
    const int* __restrict__ batch, const float* __restrict__ Wlin,
    const float* __restrict__ blin, float* __restrict__ out, int n) {
  int g = blockIdx.x;
  int lo = 0, hi = n;
  while (lo < hi) { int mid = (lo + hi) >> 1; if (batch[mid] < g) lo = mid + 1; else hi = mid; }
  int beg = lo;
  hi = n;
  while (lo < hi) { int mid = (lo + hi) >> 1; if (batch[mid] < g + 1) lo = mid + 1; else hi = mid; }
  int end = lo;

  float w[8];
  #pragma unroll
  for (int c = 0; c < 8; c++) w[c] = Wlin[c];

  float acc = 0.f;
  int t = threadIdx.x;
  for (int i = beg + t; i < end; i += 256) {
    const float4* hp = reinterpret_cast<const float4*>(h + (long)i * 8);
    float4 v0 = hp[0], v1 = hp[1];
    acc += v0.x * w[0] + v0.y * w[1] + v0.z * w[2] + v0.w * w[3]
         + v1.x * w[4] + v1.y * w[5] + v1.z * w[6] + v1.w * w[7];
  }
  #pragma unroll
  for (int off = 32; off; off >>= 1) acc += __shfl_down(acc, off, 64);
  __shared__ float sh[4];
  if ((t & 63) == 0) sh[t >> 6] = acc;
  __syncthreads();
  if (t == 0) {
    float total = sh[0] + sh[1] + sh[2] + sh[3];
    float cnt = (float)(end - beg);
    out[g] = total / fmaxf(cnt, 1.f) + blin[0];
  }
}

extern "C" void kernel_launch(void* const* d_in, const int* in_sizes, int n_in,
                              void* d_out, int out_size, void* d_ws, size_t ws_size,
                              hipStream_t stream) {
  (void)n_in; (void)ws_size;
  const float* x    = (const float*)d_in[0];
  const int*   ei   = (const int*)d_in[1];
  const int*   batch= (const int*)d_in[2];
  const float* W1l  = (const float*)d_in[3];
  const float* W1r  = (const float*)d_in[4];
  const float* a1   = (const float*)d_in[5];
  const float* b1   = (const float*)d_in[6];
  const float* W2l  = (const float*)d_in[7];
  const float* W2r  = (const float*)d_in[8];
  const float* a2   = (const float*)d_in[9];
  const float* b2   = (const float*)d_in[10];
  const float* Wlin = (const float*)d_in[11];
  const float* blin = (const float*)d_in[12];
  float* out = (float*)d_out;

  int N = in_sizes[0] / 128;
  int E = in_sizes[1] / 2;
  int G = out_size;                 // 256 graphs
  int ET = E + N;                   // edges incl self loops
  int NBu = (N + 255) >> 8;         // used buckets (256 nodes each), <= NBS
  int chunk = (ET + NBLK - 1) / NBLK;
  int nA = NBS * NBLK;              // 131072

  char* ws = (char*)d_ws;
  size_t off = 0;
  auto alloc = [&](size_t bytes) {
    void* p = ws + off; off = (off + bytes + 255) & ~(size_t)255; return p;
  };
  int* csr_ptr = (int*)alloc((size_t)(N + 1) * 4);
  int* A       = (int*)alloc((size_t)(nA + 1) * 4);
  int* bsum    = (int*)alloc(512 * 4);
  int* csr_src = (int*)alloc((size_t)ET * 4);
  // union: packed pairs (ET*4 B) time-shared with feature buffers (N*176 B)
  size_t featBytes = (size_t)N * (32 + 64 + 16 + 32 + 32);
  size_t pairBytes = (size_t)ET * 4;
  char* u = (char*)alloc(pairBytes > featBytes ? pairBytes : featBytes);
  int* pairs = (int*)u;
  unsigned* xl1b = (unsigned*)u;                         // N*8 uints (bf16 x16)
  float* xr1     = (float*)(u + (size_t)N * 32);         // N*16 f32
  unsigned* xl2b = (unsigned*)(u + (size_t)N * 96);      // N*4 uints (bf16 x8)
  float* xr2     = (float*)(u + (size_t)N * 112);        // N*8 f32
  float* h2      = (float*)(u + (size_t)N * 144);        // N*8 f32

  k_bin_count<<<NBLK, 256, 0, stream>>>(ei, E, ET, chunk, A);
  k_reduce<<<(nA + 255) / 256, 256, 0, stream>>>(A, bsum, nA);
  k_scan_bsum<<<1, 512, 0, stream>>>(bsum, (nA + 255) / 256);
  k_scan_apply<<<(nA + 255) / 256, 256, 0, stream>>>(A, bsum, nA);
  k_bin_scatter<<<NBLK, 256, 0, stream>>>(ei, E, ET, chunk, A, pairs);
  k_csr_build<<<NBu, 256, 0, stream>>>(pairs, A, csr_ptr, csr_src, N, NBu);
  k_gemm1<<<(N + 63) / 64, 256, 0, stream>>>(x, W1l, W1r, xl1b, xr1, N);
  k_edge1<<<(N + 63) / 64, 256, 0, stream>>>(csr_ptr, csr_src, xl1b, xr1, a1, b1,
                                             W2l, W2r, xl2b, xr2, N);
  k_edge2<<<(N + 63) / 64, 256, 0, stream>>>(csr_ptr, csr_src, xl2b, xr2, a2, b2, h2, N);
  k_pool_final<<<G, 256, 0, stream>>>(h2, batch, Wlin, blin, out, N);
}

// Round 8
// 179.318 us; speedup vs baseline: 1.3473x; 1.0136x over previous
//
#include <hip/hip_runtime.h>
#include <hip/hip_bf16.h>
#include <math.h>

#define NBLK 1024  // binning blocks
#define NBS  512   // bucket slots (pow2 bucket = 256 nodes => 391 used)

// ---------------- bf16 helpers (RNE) ----------------
__device__ __forceinline__ unsigned bfr(float x) {      // f32 -> bf16 bits (RNE)
  unsigned u = __float_as_uint(x);
  return (u + 0x7fffu + ((u >> 16) & 1u)) >> 16;
}
__device__ __forceinline__ unsigned bfpk(float lo, float hi) {
  return (bfr(hi) << 16) | bfr(lo);
}
__device__ __forceinline__ float bflo(unsigned u) { return __uint_as_float(u << 16); }
__device__ __forceinline__ float bfhi(unsigned u) { return __uint_as_float(u & 0xffff0000u); }

// ---------------- binned CSR build (no global atomics, pow2 buckets) ----------------
__global__ __launch_bounds__(256) void k_bin_count(const int* __restrict__ ei,
    int E, int ET, int chunk, int* __restrict__ A) {
  __shared__ int lh[NBS];
  int t = threadIdx.x;
  lh[t] = 0; lh[t + 256] = 0;
  __syncthreads();
  int beg = blockIdx.x * chunk, end = min(beg + chunk, ET);
  for (int i = beg + t; i < end; i += 256) {
    int d = (i < E) ? ei[E + i] : (i - E);      // self loop for i>=E
    atomicAdd(&lh[d >> 8], 1);
  }
  __syncthreads();
  A[t * NBLK + blockIdx.x] = lh[t];
  A[(t + 256) * NBLK + blockIdx.x] = lh[t + 256];
}

// block-sum of 1024 consecutive ints (4 per thread)
__global__ void k_reduce4(const int* __restrict__ a, int* bsum, int n) {
  int t = threadIdx.x;
  int base = blockIdx.x * 1024 + t * 4;
  int v = 0;
  if (base + 3 < n) {
    int4 q = *reinterpret_cast<const int4*>(a + base);
    v = q.x + q.y + q.z + q.w;
  } else {
    for (int k = 0; k < 4; k++) if (base + k < n) v += a[base + k];
  }
  #pragma unroll
  for (int off = 32; off; off >>= 1) v += __shfl_down(v, off, 64);
  __shared__ int sh[4];
  if ((t & 63) == 0) sh[t >> 6] = v;
  __syncthreads();
  if (t == 0) bsum[blockIdx.x] = sh[0] + sh[1] + sh[2] + sh[3];
}

// single-block inclusive->exclusive scan of block sums (nb <= 512)
__global__ void k_scan_bsum(int* bsum, int nb) {
  __shared__ int sh[512];
  int t = threadIdx.x;
  int v = (t < nb) ? bsum[t] : 0;
  sh[t] = v; __syncthreads();
  for (int off = 1; off < 512; off <<= 1) {
    int add = (t >= off) ? sh[t - off] : 0;
    __syncthreads();
    sh[t] += add;
    __syncthreads();
  }
  if (t < nb) bsum[t] = sh[t] - v;   // exclusive
}

// in-place exclusive scan apply, 4 elems/thread; writes A[n] = total
__global__ void k_scan_apply4(int* A, const int* __restrict__ bsum, int n) {
  __shared__ int sh[256];
  int t = threadIdx.x;
  int base = blockIdx.x * 1024 + t * 4;
  int4 q = *reinterpret_cast<const int4*>(A + base);   // n is multiple of 1024
  int tsum = q.x + q.y + q.z + q.w;
  sh[t] = tsum; __syncthreads();
  for (int off = 1; off < 256; off <<= 1) {
    int add = (t >= off) ? sh[t - off] : 0;
    __syncthreads();
    sh[t] += add;
    __syncthreads();
  }
  int excl = sh[t] - tsum + bsum[blockIdx.x];
  int4 w;
  w.x = excl; w.y = w.x + q.x; w.z = w.y + q.y; w.w = w.z + q.z;
  *reinterpret_cast<int4*>(A + base) = w;
  if (base + 4 == n) A[n] = w.w + q.w;
}

__global__ __launch_bounds__(256) void k_bin_scatter(const int* __restrict__ ei,
    int E, int ET, int chunk, const int* __restrict__ A, int* __restrict__ pairs) {
  __shared__ int cur[NBS];
  int t = threadIdx.x;
  cur[t]       = A[t * NBLK + blockIdx.x];
  cur[t + 256] = A[(t + 256) * NBLK + blockIdx.x];
  __syncthreads();
  int beg = blockIdx.x * chunk, end = min(beg + chunk, ET);
  for (int i = beg + t; i < end; i += 256) {
    int s, d;
    if (i < E) { s = ei[i]; d = ei[E + i]; } else { s = d = i - E; }
    int pos = atomicAdd(&cur[d >> 8], 1);
    pairs[pos] = (s << 8) | (d & 255);        // src<2^24, local dst in 8 bits
  }
}

__global__ __launch_bounds__(512) void k_csr_build(const int* __restrict__ pairs,
    const int* __restrict__ A, int* __restrict__ csr_ptr, int* __restrict__ csr_src,
    int N, int NBu) {
  __shared__ int cnt[256];
  __shared__ int cur[256];
  __shared__ int sh[256];
  int b = blockIdx.x, t = threadIdx.x;
  int base = A[b * NBLK], endp = A[(b + 1) * NBLK];
  int node0 = b << 8;
  if (t < 256) cnt[t] = 0;
  __syncthreads();
  for (int e = base + t; e < endp; e += 512)
    atomicAdd(&cnt[pairs[e] & 255], 1);
  __syncthreads();
  int v = (t < 256) ? cnt[t] : 0;
  if (t < 256) sh[t] = v;
  __syncthreads();
  for (int off = 1; off < 256; off <<= 1) {
    int add = (t >= off && t < 256) ? sh[t - off] : 0;
    __syncthreads();
    if (t < 256) sh[t] += add;
    __syncthreads();
  }
  if (t < 256) {
    int excl = sh[t] - v;
    if (node0 + t < N) csr_ptr[node0 + t] = base + excl;
    cur[t] = base + excl;
  }
  if (b == NBu - 1 && t == 0) csr_ptr[N] = endp;
  __syncthreads();
  for (int e = base + t; e < endp; e += 512) {
    int p = pairs[e];
    int pos = atomicAdd(&cur[p & 255], 1);
    csr_src[pos] = ((unsigned)p) >> 8;
  }
}

// ----- layer 1 transform: xl1(bf16) = x@W1l, xr1(f32) = x@W1r -----
__global__ __launch_bounds__(256) void k_gemm1(const float* __restrict__ x,
    const float* __restrict__ Wl, const float* __restrict__ Wr,
    unsigned* __restrict__ xlb, float* __restrict__ xr, int n) {
  __shared__ float xs[64 * 132];
  __shared__ float Ws[128 * 32];
  int t = threadIdx.x;
  int r0 = blockIdx.x * 64;
  #pragma unroll
  for (int i = 0; i < 8; i++) {
    int idx = t + i * 256;
    int k = idx >> 4, c = idx & 15;
    Ws[k * 32 + c]      = Wl[idx];
    Ws[k * 32 + 16 + c] = Wr[idx];
  }
  #pragma unroll
  for (int i = 0; i < 8; i++) {
    int v = t + i * 256;
    int row = v >> 5;
    int col4 = v & 31;
    float4 val = make_float4(0.f, 0.f, 0.f, 0.f);
    if (r0 + row < n)
      val = reinterpret_cast<const float4*>(x)[(long)(r0 + row) * 32 + col4];
    float* dst = &xs[row * 132 + col4 * 4];
    dst[0] = val.x; dst[1] = val.y; dst[2] = val.z; dst[3] = val.w;
  }
  __syncthreads();
  int g = t >> 2;
  int sub = t & 3;
  float acc[8] = {0.f,0.f,0.f,0.f,0.f,0.f,0.f,0.f};
  #pragma unroll 4
  for (int k = 0; k < 128; k++) {
    float xv = xs[g * 132 + k];
    const float4* wp = reinterpret_cast<const float4*>(&Ws[k * 32 + sub * 8]);
    float4 w0 = wp[0], w1 = wp[1];
    acc[0] += xv * w0.x; acc[1] += xv * w0.y; acc[2] += xv * w0.z; acc[3] += xv * w0.w;
    acc[4] += xv * w1.x; acc[5] += xv * w1.y; acc[6] += xv * w1.z; acc[7] += xv * w1.w;
  }
  int row = r0 + g;
  if (row < n) {
    if (sub < 2) {       // xl channels sub*8 .. sub*8+7 as bf16
      uint4 pk;
      pk.x = bfpk(acc[0], acc[1]); pk.y = bfpk(acc[2], acc[3]);
      pk.z = bfpk(acc[4], acc[5]); pk.w = bfpk(acc[6], acc[7]);
      reinterpret_cast<uint4*>(xlb)[(long)row * 2 + sub] = pk;
    } else {             // xr channels (sub-2)*8 .. +7 as f32
      float4* o4 = reinterpret_cast<float4*>(&xr[(long)row * 16 + (sub - 2) * 8]);
      o4[0] = make_float4(acc[0], acc[1], acc[2], acc[3]);
      o4[1] = make_float4(acc[4], acc[5], acc[6], acc[7]);
    }
  }
}

// ---------------- quad DPP helpers (cross-lane within quad, VALU only) ----------------
template<int CTRL>
__device__ __forceinline__ float dpp_mov(float x) {
  return __int_as_float(__builtin_amdgcn_update_dpp(0, __float_as_int(x), CTRL, 0xF, 0xF, true));
}
__device__ __forceinline__ float quad_sum(float x) {
  x += dpp_mov<0xB1>(x);   // xor 1
  x += dpp_mov<0x4E>(x);   // xor 2
  return x;
}
__device__ __forceinline__ float quad_max(float x) {
  x = fmaxf(x, dpp_mov<0xB1>(x));
  x = fmaxf(x, dpp_mov<0x4E>(x));
  return x;
}

// ------- layer-1 edge aggregation: 4 lanes/node, bf16 gather, 3-slot pipeline, fused gemm2 -------
// leaky(z) = 0.6z + 0.4|z| (slope 0.2). Defer-max: m=0 unless e>m+25 (exact fallback).
__global__ __launch_bounds__(256) void k_edge1(const int* __restrict__ csr_ptr,
    const int* __restrict__ csr_src, const unsigned* __restrict__ xlb,
    const float* __restrict__ xr, const float* __restrict__ att,
    const float* __restrict__ bias, const float* __restrict__ W2l,
    const float* __restrict__ W2r, unsigned* __restrict__ xl2b,
    float* __restrict__ xr2, int n) {
  __shared__ float Ws[16 * 16];    // [k][j]: j<8 -> W2l, j>=8 -> W2r
  int t = threadIdx.x;
  if (t < 128) {
    int k = t >> 3, j = t & 7;
    Ws[k * 16 + j]     = W2l[t];
    Ws[k * 16 + 8 + j] = W2r[t];
  }
  __syncthreads();
  int node = blockIdx.x * 64 + (t >> 2);
  int sub = t & 3;
  if (node >= n) return;
  int beg = csr_ptr[node], end = csr_ptr[node + 1];
  float xrv[16], av[16], nu[16];
  const float4* xrp = reinterpret_cast<const float4*>(xr + (long)node * 16);
  #pragma unroll
  for (int q = 0; q < 4; q++) {
    float4 v = xrp[q];
    xrv[q*4] = v.x; xrv[q*4+1] = v.y; xrv[q*4+2] = v.z; xrv[q*4+3] = v.w;
  }
  #pragma unroll
  for (int c = 0; c < 16; c++) { av[c] = att[c]; nu[c] = 0.f; }
  float m = 0.f, s = 0.f;

  auto PROCESS = [&](const uint4& ra, const uint4& rb) {
    unsigned uu[8] = {ra.x, ra.y, ra.z, ra.w, rb.x, rb.y, rb.z, rb.w};
    float xlv[16];
    #pragma unroll
    for (int k = 0; k < 8; k++) { xlv[2*k] = bflo(uu[k]); xlv[2*k+1] = bfhi(uu[k]); }
    float e1a = 0.f, e1b = 0.f, e2a = 0.f, e2b = 0.f;
    #pragma unroll
    for (int c = 0; c < 8; c++) {
      float za = xlv[c] + xrv[c];
      float zb = xlv[c + 8] + xrv[c + 8];
      e1a += av[c] * za;       e2a += av[c] * fabsf(za);
      e1b += av[c + 8] * zb;   e2b += av[c + 8] * fabsf(zb);
    }
    float e = 0.6f * (e1a + e1b) + 0.4f * (e2a + e2b);
    if (e > m + 25.f) {                       // rare exact rescale fallback
      float sc = __expf(m - e);
      s *= sc;
      #pragma unroll
      for (int c = 0; c < 16; c++) nu[c] *= sc;
      m = e;
    }
    float pe = __expf(e - m);
    s += pe;
    #pragma unroll
    for (int c = 0; c < 16; c++) nu[c] += pe * xlv[c];
  };

  int i = beg + sub;
  int i3 = i + 12;
  int x3 = 0;
  uint4 a0, b0, a1, b1, a2, b2;
  if (i < end) {
    int x0 = csr_src[i];
    const uint4* p = reinterpret_cast<const uint4*>(xlb + (long)x0 * 8);
    a0 = p[0]; b0 = p[1];
  }
  if (i + 4 < end) {
    int x1 = csr_src[i + 4];
    const uint4* p = reinterpret_cast<const uint4*>(xlb + (long)x1 * 8);
    a1 = p[0]; b1 = p[1];
  }
  if (i + 8 < end) {
    int x2 = csr_src[i + 8];
    const uint4* p = reinterpret_cast<const uint4*>(xlb + (long)x2 * 8);
    a2 = p[0]; b2 = p[1];
  }
  if (i3 < end) x3 = csr_src[i3];

  #define STEP1(AA, BB)                                                         \
    if (i >= end) break;                                                        \
    PROCESS(AA, BB);                                                            \
    if (i3 < end) {                                                             \
      const uint4* p = reinterpret_cast<const uint4*>(xlb + (long)x3 * 8);      \
      AA = p[0]; BB = p[1];                                                     \
    }                                                                           \
    i += 4; i3 += 4;                                                            \
    if (i3 < end) x3 = csr_src[i3];

  for (;;) {
    STEP1(a0, b0)
    STEP1(a1, b1)
    STEP1(a2, b2)
  }
  #undef STEP1

  // merge the 4 per-lane chains within the quad (exact)
  float M = quad_max(m);
  float sc = __expf(m - M);
  float S = quad_sum(s * sc);
  float o[16];
  #pragma unroll
  for (int c = 0; c < 16; c++) o[c] = quad_sum(nu[c] * sc);
  float inv = 1.f / fmaxf(S, 1e-16f);
  #pragma unroll
  for (int c = 0; c < 16; c++) o[c] = fmaxf(o[c] * inv + bias[c], 0.f);  // relu(h1)
  // fused layer-2 transform: this lane computes its 4 output channels.
  float r[4] = {0.f, 0.f, 0.f, 0.f};
  int j0 = sub * 4;
  #pragma unroll
  for (int k = 0; k < 16; k++) {
    float ok = o[k];
    const float* wk = &Ws[k * 16 + j0];
    r[0] += ok * wk[0]; r[1] += ok * wk[1]; r[2] += ok * wk[2]; r[3] += ok * wk[3];
  }
  if (sub < 2) {   // xl2 bf16: 4 vals -> uint2 (8 B)
    uint2 pk; pk.x = bfpk(r[0], r[1]); pk.y = bfpk(r[2], r[3]);
    reinterpret_cast<uint2*>(xl2b)[(long)node * 2 + sub] = pk;
  } else {         // xr2 f32
    reinterpret_cast<float4*>(xr2)[(long)node * 2 + (sub - 2)] =
        make_float4(r[0], r[1], r[2], r[3]);
  }
}

// ------- layer-2 edge aggregation: 4 lanes/node, bf16 gather, 3-slot pipeline -------
__global__ __launch_bounds__(256) void k_edge2(const int* __restrict__ csr_ptr,
    const int* __restrict__ csr_src, const unsigned* __restrict__ xlb,
    const float* __restrict__ xr, const float* __restrict__ att,
    const float* __restrict__ bias, float* __restrict__ out, int n) {
  int t = threadIdx.x;
  int node = blockIdx.x * 64 + (t >> 2);
  int sub = t & 3;
  if (node >= n) return;
  int beg = csr_ptr[node], end = csr_ptr[node + 1];
  float xrv[8], av[8], nu[8];
  const float4* xrp = reinterpret_cast<const float4*>(xr + (long)node * 8);
  {
    float4 v0 = xrp[0], v1 = xrp[1];
    xrv[0]=v0.x; xrv[1]=v0.y; xrv[2]=v0.z; xrv[3]=v0.w;
    xrv[4]=v1.x; xrv[5]=v1.y; xrv[6]=v1.z; xrv[7]=v1.w;
  }
  #pragma unroll
  for (int c = 0; c < 8; c++) { av[c] = att[c]; nu[c] = 0.f; }
  float m = 0.f, s = 0.f;

  auto PROCESS = [&](const uint4& ra) {
    unsigned uu[4] = {ra.x, ra.y, ra.z, ra.w};
    float xlv[8];
    #pragma unroll
    for (int k = 0; k < 4; k++) { xlv[2*k] = bflo(uu[k]); xlv[2*k+1] = bfhi(uu[k]); }
    float e1a = 0.f, e1b = 0.f, e2a = 0.f, e2b = 0.f;
    #pragma unroll
    for (int c = 0; c < 4; c++) {
      float za = xlv[c] + xrv[c];
      float zb = xlv[c + 4] + xrv[c + 4];
      e1a += av[c] * za;       e2a += av[c] * fabsf(za);
      e1b += av[c + 4] * zb;   e2b += av[c + 4] * fabsf(zb);
    }
    float e = 0.6f * (e1a + e1b) + 0.4f * (e2a + e2b);
    if (e > m + 25.f) {
      float sc = __expf(m - e);
      s *= sc;
      #pragma unroll
      for (int c = 0; c < 8; c++) nu[c] *= sc;
      m = e;
    }
    float pe = __expf(e - m);
    s += pe;
    #pragma unroll
    for (int c = 0; c < 8; c++) nu[c] += pe * xlv[c];
  };

  int i = beg + sub;
  int i3 = i + 12;
  int x3 = 0;
  uint4 r0, r1, r2;
  if (i < end)     r0 = reinterpret_cast<const uint4*>(xlb)[csr_src[i]];
  if (i + 4 < end) r1 = reinterpret_cast<const uint4*>(xlb)[csr_src[i + 4]];
  if (i + 8 < end) r2 = reinterpret_cast<const uint4*>(xlb)[csr_src[i + 8]];
  if (i3 < end) x3 = csr_src[i3];

  #define STEP2(RR)                                                   \
    if (i >= end) break;                                              \
    PROCESS(RR);                                                      \
    if (i3 < end) RR = reinterpret_cast<const uint4*>(xlb)[x3];       \
    i += 4; i3 += 4;                                                  \
    if (i3 < end) x3 = csr_src[i3];

  for (;;) {
    STEP2(r0)
    STEP2(r1)
    STEP2(r2)
  }
  #undef STEP2

  float M = quad_max(m);
  float sc = __expf(m - M);
  float S = quad_sum(s * sc);
  float o[8];
  #pragma unroll
  for (int c = 0; c < 8; c++) o[c] = quad_sum(nu[c] * sc);
  float inv = 1.f / fmaxf(S, 1e-16f);
  #pragma unroll
  for (int c = 0; c < 8; c++) o[c] = fmaxf(o[c] * inv + bias[c], 0.f);
  if (sub < 2) {
    float4* po = reinterpret_cast<float4*>(out + (long)node * 8 + sub * 4);
    *po = make_float4(o[sub*4], o[sub*4+1], o[sub*4+2], o[sub*4+3]);
  }
}

// ---------------- fused mean pool + linear: one block per graph ----------------
__global__ __launch_bounds__(256) void k_pool_final(const float* __restrict__ h,
    const int* __restrict__ batch, const float* __restrict__ Wlin,
    const float* __restrict__ blin, float* __restrict__ out, int n) {
  int g = blockIdx.x;
  int lo = 0, hi = n;
  while (lo < hi) { int mid = (lo + hi) >> 1; if (batch[mid] < g) lo = mid + 1; else hi = mid; }
  int beg = lo;
  hi = n;
  while (lo < hi) { int mid = (lo + hi) >> 1; if (batch[mid] < g + 1) lo = mid + 1; else hi = mid; }
  int end = lo;

  float w[8];
  #pragma unroll
  for (int c = 0; c < 8; c++) w[c] = Wlin[c];

  float acc = 0.f;
  int t = threadIdx.x;
  for (int i = beg + t; i < end; i += 256) {
    const float4* hp = reinterpret_cast<const float4*>(h + (long)i * 8);
    float4 v0 = hp[0], v1 = hp[1];
    acc += v0.x * w[0] + v0.y * w[1] + v0.z * w[2] + v0.w * w[3]
         + v1.x * w[4] + v1.y * w[5] + v1.z * w[6] + v1.w * w[7];
  }
  #pragma unroll
  for (int off = 32; off; off >>= 1) acc += __shfl_down(acc, off, 64);
  __shared__ float sh[4];
  if ((t & 63) == 0) sh[t >> 6] = acc;
  __syncthreads();
  if (t == 0) {
    float total = sh[0] + sh[1] + sh[2] + sh[3];
    float cnt = (float)(end - beg);
    out[g] = total / fmaxf(cnt, 1.f) + blin[0];
  }
}

extern "C" void kernel_launch(void* const* d_in, const int* in_sizes, int n_in,
                              void* d_out, int out_size, void* d_ws, size_t ws_size,
                              hipStream_t stream) {
  (void)n_in; (void)ws_size;
  const float* x    = (const float*)d_in[0];
  const int*   ei   = (const int*)d_in[1];
  const int*   batch= (const int*)d_in[2];
  const float* W1l  = (const float*)d_in[3];
  const float* W1r  = (const float*)d_in[4];
  const float* a1   = (const float*)d_in[5];
  const float* b1   = (const float*)d_in[6];
  const float* W2l  = (const float*)d_in[7];
  const float* W2r  = (const float*)d_in[8];
  const float* a2   = (const float*)d_in[9];
  const float* b2   = (const float*)d_in[10];
  const float* Wlin = (const float*)d_in[11];
  const float* blin = (const float*)d_in[12];
  float* out = (float*)d_out;

  int N = in_sizes[0] / 128;
  int E = in_sizes[1] / 2;
  int G = out_size;                 // 256 graphs
  int ET = E + N;                   // edges incl self loops
  int NBu = (N + 255) >> 8;         // used buckets (256 nodes each), <= NBS
  int chunk = (ET + NBLK - 1) / NBLK;
  int nA = NBS * NBLK;              // 524288

  char* ws = (char*)d_ws;
  size_t off = 0;
  auto alloc = [&](size_t bytes) {
    void* p = ws + off; off = (off + bytes + 255) & ~(size_t)255; return p;
  };
  int* csr_ptr = (int*)alloc((size_t)(N + 1) * 4);
  int* A       = (int*)alloc((size_t)(nA + 1) * 4);
  int* bsum    = (int*)alloc(512 * 4);
  int* csr_src = (int*)alloc((size_t)ET * 4);
  // union: packed pairs (ET*4 B) time-shared with feature buffers (N*176 B)
  size_t featBytes = (size_t)N * (32 + 64 + 16 + 32 + 32);
  size_t pairBytes = (size_t)ET * 4;
  char* u = (char*)alloc(pairBytes > featBytes ? pairBytes : featBytes);
  int* pairs = (int*)u;
  unsigned* xl1b = (unsigned*)u;                         // N*8 uints (bf16 x16)
  float* xr1     = (float*)(u + (size_t)N * 32);         // N*16 f32
  unsigned* xl2b = (unsigned*)(u + (size_t)N * 96);      // N*4 uints (bf16 x8)
  float* xr2     = (float*)(u + (size_t)N * 112);        // N*8 f32
  float* h2      = (float*)(u + (size_t)N * 144);        // N*8 f32

  k_bin_count<<<NBLK, 256, 0, stream>>>(ei, E, ET, chunk, A);
  k_reduce4<<<nA / 1024, 256, 0, stream>>>(A, bsum, nA);
  k_scan_bsum<<<1, 512, 0, stream>>>(bsum, nA / 1024);
  k_scan_apply4<<<nA / 1024, 256, 0, stream>>>(A, bsum, nA);
  k_bin_scatter<<<NBLK, 256, 0, stream>>>(ei, E, ET, chunk, A, pairs);
  k_csr_build<<<NBu, 512, 0, stream>>>(pairs, A, csr_ptr, csr_src, N, NBu);
  k_gemm1<<<(N + 63) / 64, 256, 0, stream>>>(x, W1l, W1r, xl1b, xr1, N);
  k_edge1<<<(N + 63) / 64, 256, 0, stream>>>(csr_ptr, csr_src, xl1b, xr1, a1, b1,
                                             W2l, W2r, xl2b, xr2, N);
  k_edge2<<<(N + 63) / 64, 256, 0, stream>>>(csr_ptr, csr_src, xl2b, xr2, a2, b2, h2, N);
  k_pool_final<<<G, 256, 0, stream>>>(h2, batch, Wlin, blin, out, N);
}

// Round 9
// 161.867 us; speedup vs baseline: 1.4926x; 1.1078x over previous
//
#include <hip/hip_runtime.h>
#include <hip/hip_bf16.h>
#include <math.h>

#define NBLK 256   // binning chunks/blocks (keeps ~100B per (bucket,block) stream)
#define NBS  512   // bucket slots (pow2 bucket = 256 nodes => 391 used)

// ---------------- bf16 helpers (RNE) ----------------
__device__ __forceinline__ unsigned bfr(float x) {      // f32 -> bf16 bits (RNE)
  unsigned u = __float_as_uint(x);
  return (u + 0x7fffu + ((u >> 16) & 1u)) >> 16;
}
__device__ __forceinline__ unsigned bfpk(float lo, float hi) {
  return (bfr(hi) << 16) | bfr(lo);
}
__device__ __forceinline__ float bflo(unsigned u) { return __uint_as_float(u << 16); }
__device__ __forceinline__ float bfhi(unsigned u) { return __uint_as_float(u & 0xffff0000u); }

// ---------------- binned CSR build (no global atomics, pow2 buckets) ----------------
// 256 blocks x 1024 threads: 16 waves/CU hides LDS-atomic + store latency while
// keeping per-(bucket,block) output streams ~100B (write-combining friendly).
__global__ __launch_bounds__(1024) void k_bin_count(const int* __restrict__ ei,
    int E, int ET, int chunk, int* __restrict__ A) {
  __shared__ int lh[NBS];
  int t = threadIdx.x;
  if (t < NBS) lh[t] = 0;
  __syncthreads();
  int beg = blockIdx.x * chunk, end = min(beg + chunk, ET);
  for (int i = beg + t; i < end; i += 1024) {
    int d = (i < E) ? ei[E + i] : (i - E);      // self loop for i>=E
    atomicAdd(&lh[d >> 8], 1);
  }
  __syncthreads();
  if (t < NBS) A[t * NBLK + blockIdx.x] = lh[t];
}

// block-sum of 1024 consecutive ints (4 per thread)
__global__ void k_reduce4(const int* __restrict__ a, int* bsum, int n) {
  int t = threadIdx.x;
  int base = blockIdx.x * 1024 + t * 4;
  int v = 0;
  if (base + 3 < n) {
    int4 q = *reinterpret_cast<const int4*>(a + base);
    v = q.x + q.y + q.z + q.w;
  } else {
    for (int k = 0; k < 4; k++) if (base + k < n) v += a[base + k];
  }
  #pragma unroll
  for (int off = 32; off; off >>= 1) v += __shfl_down(v, off, 64);
  __shared__ int sh[4];
  if ((t & 63) == 0) sh[t >> 6] = v;
  __syncthreads();
  if (t == 0) bsum[blockIdx.x] = sh[0] + sh[1] + sh[2] + sh[3];
}

// single-block inclusive->exclusive scan of block sums (nb <= 512)
__global__ void k_scan_bsum(int* bsum, int nb) {
  __shared__ int sh[512];
  int t = threadIdx.x;
  int v = (t < nb) ? bsum[t] : 0;
  sh[t] = v; __syncthreads();
  for (int off = 1; off < 512; off <<= 1) {
    int add = (t >= off) ? sh[t - off] : 0;
    __syncthreads();
    sh[t] += add;
    __syncthreads();
  }
  if (t < nb) bsum[t] = sh[t] - v;   // exclusive
}

// in-place exclusive scan apply, 4 elems/thread; writes A[n] = total
__global__ void k_scan_apply4(int* A, const int* __restrict__ bsum, int n) {
  __shared__ int sh[256];
  int t = threadIdx.x;
  int base = blockIdx.x * 1024 + t * 4;
  int4 q = *reinterpret_cast<const int4*>(A + base);   // n is multiple of 1024
  int tsum = q.x + q.y + q.z + q.w;
  sh[t] = tsum; __syncthreads();
  for (int off = 1; off < 256; off <<= 1) {
    int add = (t >= off) ? sh[t - off] : 0;
    __syncthreads();
    sh[t] += add;
    __syncthreads();
  }
  int excl = sh[t] - tsum + bsum[blockIdx.x];
  int4 w;
  w.x = excl; w.y = w.x + q.x; w.z = w.y + q.y; w.w = w.z + q.z;
  *reinterpret_cast<int4*>(A + base) = w;
  if (base + 4 == n) A[n] = w.w + q.w;
}

__global__ __launch_bounds__(1024) void k_bin_scatter(const int* __restrict__ ei,
    int E, int ET, int chunk, const int* __restrict__ A, int* __restrict__ pairs) {
  __shared__ int cur[NBS];
  int t = threadIdx.x;
  if (t < NBS) cur[t] = A[t * NBLK + blockIdx.x];
  __syncthreads();
  int beg = blockIdx.x * chunk, end = min(beg + chunk, ET);
  for (int i = beg + t; i < end; i += 1024) {
    int s, d;
    if (i < E) { s = ei[i]; d = ei[E + i]; } else { s = d = i - E; }
    int pos = atomicAdd(&cur[d >> 8], 1);
    pairs[pos] = (s << 8) | (d & 255);        // src<2^24, local dst in 8 bits
  }
}

__global__ __launch_bounds__(1024) void k_csr_build(const int* __restrict__ pairs,
    const int* __restrict__ A, int* __restrict__ csr_ptr, int* __restrict__ csr_src,
    int N, int NBu) {
  __shared__ int cnt[256];
  __shared__ int cur[256];
  __shared__ int sh[256];
  int b = blockIdx.x, t = threadIdx.x;
  int base = A[b * NBLK], endp = A[(b + 1) * NBLK];
  int node0 = b << 8;
  if (t < 256) cnt[t] = 0;
  __syncthreads();
  for (int e = base + t; e < endp; e += 1024)
    atomicAdd(&cnt[pairs[e] & 255], 1);
  __syncthreads();
  int v = (t < 256) ? cnt[t] : 0;
  if (t < 256) sh[t] = v;
  __syncthreads();
  for (int off = 1; off < 256; off <<= 1) {
    int add = (t >= off && t < 256) ? sh[t - off] : 0;
    __syncthreads();
    if (t < 256) sh[t] += add;
    __syncthreads();
  }
  if (t < 256) {
    int excl = sh[t] - v;
    if (node0 + t < N) csr_ptr[node0 + t] = base + excl;
    cur[t] = base + excl;
  }
  if (b == NBu - 1 && t == 0) csr_ptr[N] = endp;
  __syncthreads();
  for (int e = base + t; e < endp; e += 1024) {
    int p = pairs[e];
    int pos = atomicAdd(&cur[p & 255], 1);
    csr_src[pos] = ((unsigned)p) >> 8;
  }
}

// ----- layer 1 transform: xl1(bf16) = x@W1l, xr1(f32) = x@W1r -----
__global__ __launch_bounds__(256) void k_gemm1(const float* __restrict__ x,
    const float* __restrict__ Wl, const float* __restrict__ Wr,
    unsigned* __restrict__ xlb, float* __restrict__ xr, int n) {
  __shared__ float xs[64 * 132];
  __shared__ float Ws[128 * 32];
  int t = threadIdx.x;
  int r0 = blockIdx.x * 64;
  #pragma unroll
  for (int i = 0; i < 8; i++) {
    int idx = t + i * 256;
    int k = idx >> 4, c = idx & 15;
    Ws[k * 32 + c]      = Wl[idx];
    Ws[k * 32 + 16 + c] = Wr[idx];
  }
  #pragma unroll
  for (int i = 0; i < 8; i++) {
    int v = t + i * 256;
    int row = v >> 5;
    int col4 = v & 31;
    float4 val = make_float4(0.f, 0.f, 0.f, 0.f);
    if (r0 + row < n)
      val = reinterpret_cast<const float4*>(x)[(long)(r0 + row) * 32 + col4];
    float* dst = &xs[row * 132 + col4 * 4];
    dst[0] = val.x; dst[1] = val.y; dst[2] = val.z; dst[3] = val.w;
  }
  __syncthreads();
  int g = t >> 2;
  int sub = t & 3;
  float acc[8] = {0.f,0.f,0.f,0.f,0.f,0.f,0.f,0.f};
  #pragma unroll 4
  for (int k = 0; k < 128; k++) {
    float xv = xs[g * 132 + k];
    const float4* wp = reinterpret_cast<const float4*>(&Ws[k * 32 + sub * 8]);
    float4 w0 = wp[0], w1 = wp[1];
    acc[0] += xv * w0.x; acc[1] += xv * w0.y; acc[2] += xv * w0.z; acc[3] += xv * w0.w;
    acc[4] += xv * w1.x; acc[5] += xv * w1.y; acc[6] += xv * w1.z; acc[7] += xv * w1.w;
  }
  int row = r0 + g;
  if (row < n) {
    if (sub < 2) {       // xl channels sub*8 .. sub*8+7 as bf16
      uint4 pk;
      pk.x = bfpk(acc[0], acc[1]); pk.y = bfpk(acc[2], acc[3]);
      pk.z = bfpk(acc[4], acc[5]); pk.w = bfpk(acc[6], acc[7]);
      reinterpret_cast<uint4*>(xlb)[(long)row * 2 + sub] = pk;
    } else {             // xr channels (sub-2)*8 .. +7 as f32
      float4* o4 = reinterpret_cast<float4*>(&xr[(long)row * 16 + (sub - 2) * 8]);
      o4[0] = make_float4(acc[0], acc[1], acc[2], acc[3]);
      o4[1] = make_float4(acc[4], acc[5], acc[6], acc[7]);
    }
  }
}

// ---------------- quad DPP helpers (cross-lane within quad, VALU only) ----------------
template<int CTRL>
__device__ __forceinline__ float dpp_mov(float x) {
  return __int_as_float(__builtin_amdgcn_update_dpp(0, __float_as_int(x), CTRL, 0xF, 0xF, true));
}
__device__ __forceinline__ float quad_sum(float x) {
  x += dpp_mov<0xB1>(x);   // xor 1
  x += dpp_mov<0x4E>(x);   // xor 2
  return x;
}
__device__ __forceinline__ float quad_max(float x) {
  x = fmaxf(x, dpp_mov<0xB1>(x));
  x = fmaxf(x, dpp_mov<0x4E>(x));
  return x;
}

// ------- layer-1 edge aggregation: 4 lanes/node, bf16 gather, 3-slot pipeline, fused gemm2 -------
// leaky(z) = 0.6z + 0.4|z| (slope 0.2). Defer-max: m=0 unless e>m+25 (exact fallback).
__global__ __launch_bounds__(256) void k_edge1(const int* __restrict__ csr_ptr,
    const int* __restrict__ csr_src, const unsigned* __restrict__ xlb,
    const float* __restrict__ xr, const float* __restrict__ att,
    const float* __restrict__ bias, const float* __restrict__ W2l,
    const float* __restrict__ W2r, unsigned* __restrict__ xl2b,
    float* __restrict__ xr2, int n) {
  __shared__ float Ws[16 * 16];    // [k][j]: j<8 -> W2l, j>=8 -> W2r
  int t = threadIdx.x;
  if (t < 128) {
    int k = t >> 3, j = t & 7;
    Ws[k * 16 + j]     = W2l[t];
    Ws[k * 16 + 8 + j] = W2r[t];
  }
  __syncthreads();
  int node = blockIdx.x * 64 + (t >> 2);
  int sub = t & 3;
  if (node >= n) return;
  int beg = csr_ptr[node], end = csr_ptr[node + 1];
  float xrv[16], av[16], nu[16];
  const float4* xrp = reinterpret_cast<const float4*>(xr + (long)node * 16);
  #pragma unroll
  for (int q = 0; q < 4; q++) {
    float4 v = xrp[q];
    xrv[q*4] = v.x; xrv[q*4+1] = v.y; xrv[q*4+2] = v.z; xrv[q*4+3] = v.w;
  }
  #pragma unroll
  for (int c = 0; c < 16; c++) { av[c] = att[c]; nu[c] = 0.f; }
  float m = 0.f, s = 0.f;

  auto PROCESS = [&](const uint4& ra, const uint4& rb) {
    unsigned uu[8] = {ra.x, ra.y, ra.z, ra.w, rb.x, rb.y, rb.z, rb.w};
    float xlv[16];
    #pragma unroll
    for (int k = 0; k < 8; k++) { xlv[2*k] = bflo(uu[k]); xlv[2*k+1] = bfhi(uu[k]); }
    float e1a = 0.f, e1b = 0.f, e2a = 0.f, e2b = 0.f;
    #pragma unroll
    for (int c = 0; c < 8; c++) {
      float za = xlv[c] + xrv[c];
      float zb = xlv[c + 8] + xrv[c + 8];
      e1a += av[c] * za;       e2a += av[c] * fabsf(za);
      e1b += av[c + 8] * zb;   e2b += av[c + 8] * fabsf(zb);
    }
    float e = 0.6f * (e1a + e1b) + 0.4f * (e2a + e2b);
    if (e > m + 25.f) {                       // rare exact rescale fallback
      float sc = __expf(m - e);
      s *= sc;
      #pragma unroll
      for (int c = 0; c < 16; c++) nu[c] *= sc;
      m = e;
    }
    float pe = __expf(e - m);
    s += pe;
    #pragma unroll
    for (int c = 0; c < 16; c++) nu[c] += pe * xlv[c];
  };

  int i = beg + sub;
  int i3 = i + 12;
  int x3 = 0;
  uint4 a0, b0, a1, b1, a2, b2;
  if (i < end) {
    int x0 = csr_src[i];
    const uint4* p = reinterpret_cast<const uint4*>(xlb + (long)x0 * 8);
    a0 = p[0]; b0 = p[1];
  }
  if (i + 4 < end) {
    int x1 = csr_src[i + 4];
    const uint4* p = reinterpret_cast<const uint4*>(xlb + (long)x1 * 8);
    a1 = p[0]; b1 = p[1];
  }
  if (i + 8 < end) {
    int x2 = csr_src[i + 8];
    const uint4* p = reinterpret_cast<const uint4*>(xlb + (long)x2 * 8);
    a2 = p[0]; b2 = p[1];
  }
  if (i3 < end) x3 = csr_src[i3];

  #define STEP1(AA, BB)                                                         \
    if (i >= end) break;                                                        \
    PROCESS(AA, BB);                                                            \
    if (i3 < end) {                                                             \
      const uint4* p = reinterpret_cast<const uint4*>(xlb + (long)x3 * 8);      \
      AA = p[0]; BB = p[1];                                                     \
    }                                                                           \
    i += 4; i3 += 4;                                                            \
    if (i3 < end) x3 = csr_src[i3];

  for (;;) {
    STEP1(a0, b0)
    STEP1(a1, b1)
    STEP1(a2, b2)
  }
  #undef STEP1

  // merge the 4 per-lane chains within the quad (exact)
  float M = quad_max(m);
  float sc = __expf(m - M);
  float S = quad_sum(s * sc);
  float o[16];
  #pragma unroll
  for (int c = 0; c < 16; c++) o[c] = quad_sum(nu[c] * sc);
  float inv = 1.f / fmaxf(S, 1e-16f);
  #pragma unroll
  for (int c = 0; c < 16; c++) o[c] = fmaxf(o[c] * inv + bias[c], 0.f);  // relu(h1)
  // fused layer-2 transform: this lane computes its 4 output channels.
  float r[4] = {0.f, 0.f, 0.f, 0.f};
  int j0 = sub * 4;
  #pragma unroll
  for (int k = 0; k < 16; k++) {
    float ok = o[k];
    const float* wk = &Ws[k * 16 + j0];
    r[0] += ok * wk[0]; r[1] += ok * wk[1]; r[2] += ok * wk[2]; r[3] += ok * wk[3];
  }
  if (sub < 2) {   // xl2 bf16: 4 vals -> uint2 (8 B)
    uint2 pk; pk.x = bfpk(r[0], r[1]); pk.y = bfpk(r[2], r[3]);
    reinterpret_cast<uint2*>(xl2b)[(long)node * 2 + sub] = pk;
  } else {         // xr2 f32
    reinterpret_cast<float4*>(xr2)[(long)node * 2 + (sub - 2)] =
        make_float4(r[0], r[1], r[2], r[3]);
  }
}

// ------- layer-2 edge aggregation: 4 lanes/node, bf16 gather, 3-slot pipeline -------
__global__ __launch_bounds__(256) void k_edge2(const int* __restrict__ csr_ptr,
    const int* __restrict__ csr_src, const unsigned* __restrict__ xlb,
    const float* __restrict__ xr, const float* __restrict__ att,
    const float* __restrict__ bias, float* __restrict__ out, int n) {
  int t = threadIdx.x;
  int node = blockIdx.x * 64 + (t >> 2);
  int sub = t & 3;
  if (node >= n) return;
  int beg = csr_ptr[node], end = csr_ptr[node + 1];
  float xrv[8], av[8], nu[8];
  const float4* xrp = reinterpret_cast<const float4*>(xr + (long)node * 8);
  {
    float4 v0 = xrp[0], v1 = xrp[1];
    xrv[0]=v0.x; xrv[1]=v0.y; xrv[2]=v0.z; xrv[3]=v0.w;
    xrv[4]=v1.x; xrv[5]=v1.y; xrv[6]=v1.z; xrv[7]=v1.w;
  }
  #pragma unroll
  for (int c = 0; c < 8; c++) { av[c] = att[c]; nu[c] = 0.f; }
  float m = 0.f, s = 0.f;

  auto PROCESS = [&](const uint4& ra) {
    unsigned uu[4] = {ra.x, ra.y, ra.z, ra.w};
    float xlv[8];
    #pragma unroll
    for (int k = 0; k < 4; k++) { xlv[2*k] = bflo(uu[k]); xlv[2*k+1] = bfhi(uu[k]); }
    float e1a = 0.f, e1b = 0.f, e2a = 0.f, e2b = 0.f;
    #pragma unroll
    for (int c = 0; c < 4; c++) {
      float za = xlv[c] + xrv[c];
      float zb = xlv[c + 4] + xrv[c + 4];
      e1a += av[c] * za;       e2a += av[c] * fabsf(za);
      e1b += av[c + 4] * zb;   e2b += av[c + 4] * fabsf(zb);
    }
    float e = 0.6f * (e1a + e1b) + 0.4f * (e2a + e2b);
    if (e > m + 25.f) {
      float sc = __expf(m - e);
      s *= sc;
      #pragma unroll
      for (int c = 0; c < 8; c++) nu[c] *= sc;
      m = e;
    }
    float pe = __expf(e - m);
    s += pe;
    #pragma unroll
    for (int c = 0; c < 8; c++) nu[c] += pe * xlv[c];
  };

  int i = beg + sub;
  int i3 = i + 12;
  int x3 = 0;
  uint4 r0, r1, r2;
  if (i < end)     r0 = reinterpret_cast<const uint4*>(xlb)[csr_src[i]];
  if (i + 4 < end) r1 = reinterpret_cast<const uint4*>(xlb)[csr_src[i + 4]];
  if (i + 8 < end) r2 = reinterpret_cast<const uint4*>(xlb)[csr_src[i + 8]];
  if (i3 < end) x3 = csr_src[i3];

  #define STEP2(RR)                                                   \
    if (i >= end) break;                                              \
    PROCESS(RR);                                                      \
    if (i3 < end) RR = reinterpret_cast<const uint4*>(xlb)[x3];       \
    i += 4; i3 += 4;                                                  \
    if (i3 < end) x3 = csr_src[i3];

  for (;;) {
    STEP2(r0)
    STEP2(r1)
    STEP2(r2)
  }
  #undef STEP2

  float M = quad_max(m);
  float sc = __expf(m - M);
  float S = quad_sum(s * sc);
  float o[8];
  #pragma unroll
  for (int c = 0; c < 8; c++) o[c] = quad_sum(nu[c] * sc);
  float inv = 1.f / fmaxf(S, 1e-16f);
  #pragma unroll
  for (int c = 0; c < 8; c++) o[c] = fmaxf(o[c] * inv + bias[c], 0.f);
  if (sub < 2) {
    float4* po = reinterpret_cast<float4*>(out + (long)node * 8 + sub * 4);
    *po = make_float4(o[sub*4], o[sub*4+1], o[sub*4+2], o[sub*4+3]);
  }
}

// ---------------- fused mean pool + linear: one block per graph ----------------
__global__ __launch_bounds__(256) void k_pool_final(const float* __restrict__ h,
    const int* __restrict__ batch, const float* __restrict__ Wlin,
    const float* __restrict__ blin, float* __restrict__ out, int n) {
  int g = blockIdx.x;
  int lo = 0, hi = n;
  while (lo < hi) { int mid = (lo + hi) >> 1; if (batch[mid] < g) lo = mid + 1; else hi = mid; }
  int beg = lo;
  hi = n;
  while (lo < hi) { int mid = (lo + hi) >> 1; if (batch[mid] < g + 1) lo = mid + 1; else hi = mid; }
  int end = lo;

  float w[8];
  #pragma unroll
  for (int c = 0; c < 8; c++) w[c] = Wlin[c];

  float acc = 0.f;
  int t = threadIdx.x;
  for (int i = beg + t; i < end; i += 256) {
    const float4* hp = reinterpret_cast<const float4*>(h + (long)i * 8);
    float4 v0 = hp[0], v1 = hp[1];
    acc += v0.x * w[0] + v0.y * w[1] + v0.z * w[2] + v0.w * w[3]
         + v1.x * w[4] + v1.y * w[5] + v1.z * w[6] + v1.w * w[7];
  }
  #pragma unroll
  for (int off = 32; off; off >>= 1) acc += __shfl_down(acc, off, 64);
  __shared__ float sh[4];
  if ((t & 63) == 0) sh[t >> 6] = acc;
  __syncthreads();
  if (t == 0) {
    float total = sh[0] + sh[1] + sh[2] + sh[3];
    float cnt = (float)(end - beg);
    out[g] = total / fmaxf(cnt, 1.f) + blin[0];
  }
}

extern "C" void kernel_launch(void* const* d_in, const int* in_sizes, int n_in,
                              void* d_out, int out_size, void* d_ws, size_t ws_size,
                              hipStream_t stream) {
  (void)n_in; (void)ws_size;
  const float* x    = (const float*)d_in[0];
  const int*   ei   = (const int*)d_in[1];
  const int*   batch= (const int*)d_in[2];
  const float* W1l  = (const float*)d_in[3];
  const float* W1r  = (const float*)d_in[4];
  const float* a1   = (const float*)d_in[5];
  const float* b1   = (const float*)d_in[6];
  const float* W2l  = (const float*)d_in[7];
  const float* W2r  = (const float*)d_in[8];
  const float* a2   = (const float*)d_in[9];
  const float* b2   = (const float*)d_in[10];
  const float* Wlin = (const float*)d_in[11];
  const float* blin = (const float*)d_in[12];
  float* out = (float*)d_out;

  int N = in_sizes[0] / 128;
  int E = in_sizes[1] / 2;
  int G = out_size;                 // 256 graphs
  int ET = E + N;                   // edges incl self loops
  int NBu = (N + 255) >> 8;         // used buckets (256 nodes each), <= NBS
  int chunk = (ET + NBLK - 1) / NBLK;
  int nA = NBS * NBLK;              // 131072

  char* ws = (char*)d_ws;
  size_t off = 0;
  auto alloc = [&](size_t bytes) {
    void* p = ws + off; off = (off + bytes + 255) & ~(size_t)255; return p;
  };
  int* csr_ptr = (int*)alloc((size_t)(N + 1) * 4);
  int* A       = (int*)alloc((size_t)(nA + 1) * 4);
  int* bsum    = (int*)alloc(512 * 4);
  int* csr_src = (int*)alloc((size_t)ET * 4);
  // union: packed pairs (ET*4 B) time-shared with feature buffers (N*176 B)
  size_t featBytes = (size_t)N * (32 + 64 + 16 + 32 + 32);
  size_t pairBytes = (size_t)ET * 4;
  char* u = (char*)alloc(pairBytes > featBytes ? pairBytes : featBytes);
  int* pairs = (int*)u;
  unsigned* xl1b = (unsigned*)u;                         // N*8 uints (bf16 x16)
  float* xr1     = (float*)(u + (size_t)N * 32);         // N*16 f32
  unsigned* xl2b = (unsigned*)(u + (size_t)N * 96);      // N*4 uints (bf16 x8)
  float* xr2     = (float*)(u + (size_t)N * 112);        // N*8 f32
  float* h2      = (float*)(u + (size_t)N * 144);        // N*8 f32

  k_bin_count<<<NBLK, 1024, 0, stream>>>(ei, E, ET, chunk, A);
  k_reduce4<<<nA / 1024, 256, 0, stream>>>(A, bsum, nA);
  k_scan_bsum<<<1, 512, 0, stream>>>(bsum, nA / 1024);
  k_scan_apply4<<<nA / 1024, 256, 0, stream>>>(A, bsum, nA);
  k_bin_scatter<<<NBLK, 1024, 0, stream>>>(ei, E, ET, chunk, A, pairs);
  k_csr_build<<<NBu, 1024, 0, stream>>>(pairs, A, csr_ptr, csr_src, N, NBu);
  k_gemm1<<<(N + 63) / 64, 256, 0, stream>>>(x, W1l, W1r, xl1b, xr1, N);
  k_edge1<<<(N + 63) / 64, 256, 0, stream>>>(csr_ptr, csr_src, xl1b, xr1, a1, b1,
                                             W2l, W2r, xl2b, xr2, N);
  k_edge2<<<(N + 63) / 64, 256, 0, stream>>>(csr_ptr, csr_src, xl2b, xr2, a2, b2, h2, N);
  k_pool_final<<<G, 256, 0, stream>>>(h2, batch, Wlin, blin, out, N);
}

// Round 10
// 155.582 us; speedup vs baseline: 1.5529x; 1.0404x over previous
//
#include <hip/hip_runtime.h>
#include <hip/hip_bf16.h>
#include <math.h>

#define NBLK 256   // binning chunks/blocks (keeps ~100B per (bucket,block) stream)
#define NBS  512   // bucket slots (pow2 bucket = 256 nodes => 391 used)

// ---------------- bf16 helpers (RNE) ----------------
__device__ __forceinline__ unsigned bfr(float x) {      // f32 -> bf16 bits (RNE)
  unsigned u = __float_as_uint(x);
  return (u + 0x7fffu + ((u >> 16) & 1u)) >> 16;
}
__device__ __forceinline__ unsigned bfpk(float lo, float hi) {
  return (bfr(hi) << 16) | bfr(lo);
}
__device__ __forceinline__ float bflo(unsigned u) { return __uint_as_float(u << 16); }
__device__ __forceinline__ float bfhi(unsigned u) { return __uint_as_float(u & 0xffff0000u); }

// ---------------- binned CSR build (no global atomics, pow2 buckets) ----------------
__global__ __launch_bounds__(1024) void k_bin_count(const int* __restrict__ ei,
    int E, int ET, int chunk, int* __restrict__ A) {
  __shared__ int lh[NBS];
  int t = threadIdx.x;
  if (t < NBS) lh[t] = 0;
  __syncthreads();
  int beg = blockIdx.x * chunk, end = min(beg + chunk, ET);
  for (int i = beg + t; i < end; i += 1024) {
    int d = (i < E) ? ei[E + i] : (i - E);      // self loop for i>=E
    atomicAdd(&lh[d >> 8], 1);
  }
  __syncthreads();
  if (t < NBS) A[t * NBLK + blockIdx.x] = lh[t];
}

// block-sum of 1024 consecutive ints (4 per thread)
__global__ void k_reduce4(const int* __restrict__ a, int* bsum, int n) {
  int t = threadIdx.x;
  int base = blockIdx.x * 1024 + t * 4;
  int v = 0;
  if (base + 3 < n) {
    int4 q = *reinterpret_cast<const int4*>(a + base);
    v = q.x + q.y + q.z + q.w;
  } else {
    for (int k = 0; k < 4; k++) if (base + k < n) v += a[base + k];
  }
  #pragma unroll
  for (int off = 32; off; off >>= 1) v += __shfl_down(v, off, 64);
  __shared__ int sh[4];
  if ((t & 63) == 0) sh[t >> 6] = v;
  __syncthreads();
  if (t == 0) bsum[blockIdx.x] = sh[0] + sh[1] + sh[2] + sh[3];
}

// single-block inclusive->exclusive scan of block sums (nb <= 512)
__global__ void k_scan_bsum(int* bsum, int nb) {
  __shared__ int sh[512];
  int t = threadIdx.x;
  int v = (t < nb) ? bsum[t] : 0;
  sh[t] = v; __syncthreads();
  for (int off = 1; off < 512; off <<= 1) {
    int add = (t >= off) ? sh[t - off] : 0;
    __syncthreads();
    sh[t] += add;
    __syncthreads();
  }
  if (t < nb) bsum[t] = sh[t] - v;   // exclusive
}

// in-place exclusive scan apply, 4 elems/thread; writes A[n] = total
__global__ void k_scan_apply4(int* A, const int* __restrict__ bsum, int n) {
  __shared__ int sh[256];
  int t = threadIdx.x;
  int base = blockIdx.x * 1024 + t * 4;
  int4 q = *reinterpret_cast<const int4*>(A + base);   // n is multiple of 1024
  int tsum = q.x + q.y + q.z + q.w;
  sh[t] = tsum; __syncthreads();
  for (int off = 1; off < 256; off <<= 1) {
    int add = (t >= off) ? sh[t - off] : 0;
    __syncthreads();
    sh[t] += add;
    __syncthreads();
  }
  int excl = sh[t] - tsum + bsum[blockIdx.x];
  int4 w;
  w.x = excl; w.y = w.x + q.x; w.z = w.y + q.y; w.w = w.z + q.z;
  *reinterpret_cast<int4*>(A + base) = w;
  if (base + 4 == n) A[n] = w.w + q.w;
}

__global__ __launch_bounds__(1024) void k_bin_scatter(const int* __restrict__ ei,
    int E, int ET, int chunk, const int* __restrict__ A, int* __restrict__ pairs) {
  __shared__ int cur[NBS];
  int t = threadIdx.x;
  if (t < NBS) cur[t] = A[t * NBLK + blockIdx.x];
  __syncthreads();
  int beg = blockIdx.x * chunk, end = min(beg + chunk, ET);
  for (int i = beg + t; i < end; i += 1024) {
    int s, d;
    if (i < E) { s = ei[i]; d = ei[E + i]; } else { s = d = i - E; }
    int pos = atomicAdd(&cur[d >> 8], 1);
    pairs[pos] = (s << 8) | (d & 255);        // src<2^24, local dst in 8 bits
  }
}

__global__ __launch_bounds__(1024) void k_csr_build(const int* __restrict__ pairs,
    const int* __restrict__ A, int* __restrict__ csr_ptr, int* __restrict__ csr_src,
    int N, int NBu) {
  __shared__ int cnt[256];
  __shared__ int cur[256];
  __shared__ int sh[256];
  int b = blockIdx.x, t = threadIdx.x;
  int base = A[b * NBLK], endp = A[(b + 1) * NBLK];
  int node0 = b << 8;
  if (t < 256) cnt[t] = 0;
  __syncthreads();
  for (int e = base + t; e < endp; e += 1024)
    atomicAdd(&cnt[pairs[e] & 255], 1);
  __syncthreads();
  int v = (t < 256) ? cnt[t] : 0;
  if (t < 256) sh[t] = v;
  __syncthreads();
  for (int off = 1; off < 256; off <<= 1) {
    int add = (t >= off && t < 256) ? sh[t - off] : 0;
    __syncthreads();
    if (t < 256) sh[t] += add;
    __syncthreads();
  }
  if (t < 256) {
    int excl = sh[t] - v;
    if (node0 + t < N) csr_ptr[node0 + t] = base + excl;
    cur[t] = base + excl;
  }
  if (b == NBu - 1 && t == 0) csr_ptr[N] = endp;
  __syncthreads();
  for (int e = base + t; e < endp; e += 1024) {
    int p = pairs[e];
    int pos = atomicAdd(&cur[p & 255], 1);
    csr_src[pos] = ((unsigned)p) >> 8;
  }
}

// ----- layer 1 transform: xl1(bf16) = x@W1l, xr1(f32) = x@W1r -----
__global__ __launch_bounds__(256) void k_gemm1(const float* __restrict__ x,
    const float* __restrict__ Wl, const float* __restrict__ Wr,
    unsigned* __restrict__ xlb, float* __restrict__ xr, int n) {
  __shared__ float xs[64 * 132];
  __shared__ float Ws[128 * 32];
  int t = threadIdx.x;
  int r0 = blockIdx.x * 64;
  #pragma unroll
  for (int i = 0; i < 8; i++) {
    int idx = t + i * 256;
    int k = idx >> 4, c = idx & 15;
    Ws[k * 32 + c]      = Wl[idx];
    Ws[k * 32 + 16 + c] = Wr[idx];
  }
  #pragma unroll
  for (int i = 0; i < 8; i++) {
    int v = t + i * 256;
    int row = v >> 5;
    int col4 = v & 31;
    float4 val = make_float4(0.f, 0.f, 0.f, 0.f);
    if (r0 + row < n)
      val = reinterpret_cast<const float4*>(x)[(long)(r0 + row) * 32 + col4];
    float* dst = &xs[row * 132 + col4 * 4];
    dst[0] = val.x; dst[1] = val.y; dst[2] = val.z; dst[3] = val.w;
  }
  __syncthreads();
  int g = t >> 2;
  int sub = t & 3;
  float acc[8] = {0.f,0.f,0.f,0.f,0.f,0.f,0.f,0.f};
  #pragma unroll 4
  for (int k = 0; k < 128; k++) {
    float xv = xs[g * 132 + k];
    const float4* wp = reinterpret_cast<const float4*>(&Ws[k * 32 + sub * 8]);
    float4 w0 = wp[0], w1 = wp[1];
    acc[0] += xv * w0.x; acc[1] += xv * w0.y; acc[2] += xv * w0.z; acc[3] += xv * w0.w;
    acc[4] += xv * w1.x; acc[5] += xv * w1.y; acc[6] += xv * w1.z; acc[7] += xv * w1.w;
  }
  int row = r0 + g;
  if (row < n) {
    if (sub < 2) {       // xl channels sub*8 .. sub*8+7 as bf16
      uint4 pk;
      pk.x = bfpk(acc[0], acc[1]); pk.y = bfpk(acc[2], acc[3]);
      pk.z = bfpk(acc[4], acc[5]); pk.w = bfpk(acc[6], acc[7]);
      reinterpret_cast<uint4*>(xlb)[(long)row * 2 + sub] = pk;
    } else {             // xr channels (sub-2)*8 .. +7 as f32
      float4* o4 = reinterpret_cast<float4*>(&xr[(long)row * 16 + (sub - 2) * 8]);
      o4[0] = make_float4(acc[0], acc[1], acc[2], acc[3]);
      o4[1] = make_float4(acc[4], acc[5], acc[6], acc[7]);
    }
  }
}

// ---------------- octet DPP helpers (cross-lane within 8 lanes, VALU only) ----------------
// 0xB1 quad_perm xor1; 0x4E quad_perm xor2; 0x141 row_half_mirror == xor4 once quads homogeneous.
template<int CTRL>
__device__ __forceinline__ float dpp_mov(float x) {
  return __int_as_float(__builtin_amdgcn_update_dpp(0, __float_as_int(x), CTRL, 0xF, 0xF, true));
}
__device__ __forceinline__ float oct_sum(float x) {
  x += dpp_mov<0xB1>(x);
  x += dpp_mov<0x4E>(x);
  x += dpp_mov<0x141>(x);
  return x;
}
__device__ __forceinline__ float oct_max(float x) {
  x = fmaxf(x, dpp_mov<0xB1>(x));
  x = fmaxf(x, dpp_mov<0x4E>(x));
  x = fmaxf(x, dpp_mov<0x141>(x));
  return x;
}

// ------- layer-1 edge aggregation: 8 lanes/node, bf16 gather, 3-slot pipeline, fused gemm2 -------
// leaky(z) = 0.6z + 0.4|z| (slope 0.2). Defer-max: m=0 unless e>m+25 (exact fallback).
__global__ __launch_bounds__(256) void k_edge1(const int* __restrict__ csr_ptr,
    const int* __restrict__ csr_src, const unsigned* __restrict__ xlb,
    const float* __restrict__ xr, const float* __restrict__ att,
    const float* __restrict__ bias, const float* __restrict__ W2l,
    const float* __restrict__ W2r, unsigned* __restrict__ xl2b,
    float* __restrict__ xr2, int n) {
  __shared__ float Ws[16 * 16];    // [k][j]: j<8 -> W2l, j>=8 -> W2r
  int t = threadIdx.x;
  if (t < 128) {
    int k = t >> 3, j = t & 7;
    Ws[k * 16 + j]     = W2l[t];
    Ws[k * 16 + 8 + j] = W2r[t];
  }
  __syncthreads();
  int node = blockIdx.x * 32 + (t >> 3);
  int sub = t & 7;
  if (node >= n) return;
  int beg = csr_ptr[node], end = csr_ptr[node + 1];
  float xrv[16], av[16], nu[16];
  const float4* xrp = reinterpret_cast<const float4*>(xr + (long)node * 16);
  #pragma unroll
  for (int q = 0; q < 4; q++) {
    float4 v = xrp[q];
    xrv[q*4] = v.x; xrv[q*4+1] = v.y; xrv[q*4+2] = v.z; xrv[q*4+3] = v.w;
  }
  #pragma unroll
  for (int c = 0; c < 16; c++) { av[c] = att[c]; nu[c] = 0.f; }
  float m = 0.f, s = 0.f;

  auto PROCESS = [&](const uint4& ra, const uint4& rb) {
    unsigned uu[8] = {ra.x, ra.y, ra.z, ra.w, rb.x, rb.y, rb.z, rb.w};
    float xlv[16];
    #pragma unroll
    for (int k = 0; k < 8; k++) { xlv[2*k] = bflo(uu[k]); xlv[2*k+1] = bfhi(uu[k]); }
    float e1a = 0.f, e1b = 0.f, e2a = 0.f, e2b = 0.f;
    #pragma unroll
    for (int c = 0; c < 8; c++) {
      float za = xlv[c] + xrv[c];
      float zb = xlv[c + 8] + xrv[c + 8];
      e1a += av[c] * za;       e2a += av[c] * fabsf(za);
      e1b += av[c + 8] * zb;   e2b += av[c + 8] * fabsf(zb);
    }
    float e = 0.6f * (e1a + e1b) + 0.4f * (e2a + e2b);
    if (e > m + 25.f) {                       // rare exact rescale fallback
      float sc = __expf(m - e);
      s *= sc;
      #pragma unroll
      for (int c = 0; c < 16; c++) nu[c] *= sc;
      m = e;
    }
    float pe = __expf(e - m);
    s += pe;
    #pragma unroll
    for (int c = 0; c < 16; c++) nu[c] += pe * xlv[c];
  };

  int i = beg + sub;
  int i3 = i + 24;                   // 3 slots x stride 8
  int x3 = 0;
  uint4 a0, b0, a1, b1, a2, b2;
  if (i < end) {
    const uint4* p = reinterpret_cast<const uint4*>(xlb + (long)csr_src[i] * 8);
    a0 = p[0]; b0 = p[1];
  }
  if (i + 8 < end) {
    const uint4* p = reinterpret_cast<const uint4*>(xlb + (long)csr_src[i + 8] * 8);
    a1 = p[0]; b1 = p[1];
  }
  if (i + 16 < end) {
    const uint4* p = reinterpret_cast<const uint4*>(xlb + (long)csr_src[i + 16] * 8);
    a2 = p[0]; b2 = p[1];
  }
  if (i3 < end) x3 = csr_src[i3];

  #define STEP1(AA, BB)                                                         \
    if (i >= end) break;                                                        \
    PROCESS(AA, BB);                                                            \
    if (i3 < end) {                                                             \
      const uint4* p = reinterpret_cast<const uint4*>(xlb + (long)x3 * 8);      \
      AA = p[0]; BB = p[1];                                                     \
    }                                                                           \
    i += 8; i3 += 8;                                                            \
    if (i3 < end) x3 = csr_src[i3];

  for (;;) {
    STEP1(a0, b0)
    STEP1(a1, b1)
    STEP1(a2, b2)
  }
  #undef STEP1

  // merge the 8 per-lane chains within the octet (exact)
  float M = oct_max(m);
  float sc = __expf(m - M);
  float S = oct_sum(s * sc);
  float o[16];
  #pragma unroll
  for (int c = 0; c < 16; c++) o[c] = oct_sum(nu[c] * sc);
  float inv = 1.f / fmaxf(S, 1e-16f);
  #pragma unroll
  for (int c = 0; c < 16; c++) o[c] = fmaxf(o[c] * inv + bias[c], 0.f);  // relu(h1)
  // fused layer-2 transform: each lane computes 2 of the 16 output channels.
  // sub<4: xl2 channels (sub*2, sub*2+1); sub>=4: xr2 channels ((sub-4)*2, +1)
  int col = (sub < 4) ? (sub * 2) : (8 + (sub - 4) * 2);
  float r0 = 0.f, r1 = 0.f;
  #pragma unroll
  for (int k = 0; k < 16; k++) {
    float ok = o[k];
    r0 += ok * Ws[k * 16 + col];
    r1 += ok * Ws[k * 16 + col + 1];
  }
  if (sub < 4) {   // xl2 bf16: 2 vals -> 1 uint
    xl2b[(long)node * 4 + sub] = bfpk(r0, r1);
  } else {         // xr2 f32: float2
    reinterpret_cast<float2*>(xr2)[(long)node * 4 + (sub - 4)] = make_float2(r0, r1);
  }
}

// ------- layer-2 edge aggregation: 8 lanes/node, bf16 gather, 3-slot pipeline -------
__global__ __launch_bounds__(256) void k_edge2(const int* __restrict__ csr_ptr,
    const int* __restrict__ csr_src, const unsigned* __restrict__ xlb,
    const float* __restrict__ xr, const float* __restrict__ att,
    const float* __restrict__ bias, float* __restrict__ out, int n) {
  int t = threadIdx.x;
  int node = blockIdx.x * 32 + (t >> 3);
  int sub = t & 7;
  if (node >= n) return;
  int beg = csr_ptr[node], end = csr_ptr[node + 1];
  float xrv[8], av[8], nu[8];
  const float4* xrp = reinterpret_cast<const float4*>(xr + (long)node * 8);
  {
    float4 v0 = xrp[0], v1 = xrp[1];
    xrv[0]=v0.x; xrv[1]=v0.y; xrv[2]=v0.z; xrv[3]=v0.w;
    xrv[4]=v1.x; xrv[5]=v1.y; xrv[6]=v1.z; xrv[7]=v1.w;
  }
  #pragma unroll
  for (int c = 0; c < 8; c++) { av[c] = att[c]; nu[c] = 0.f; }
  float m = 0.f, s = 0.f;

  auto PROCESS = [&](const uint4& ra) {
    unsigned uu[4] = {ra.x, ra.y, ra.z, ra.w};
    float xlv[8];
    #pragma unroll
    for (int k = 0; k < 4; k++) { xlv[2*k] = bflo(uu[k]); xlv[2*k+1] = bfhi(uu[k]); }
    float e1a = 0.f, e1b = 0.f, e2a = 0.f, e2b = 0.f;
    #pragma unroll
    for (int c = 0; c < 4; c++) {
      float za = xlv[c] + xrv[c];
      float zb = xlv[c + 4] + xrv[c + 4];
      e1a += av[c] * za;       e2a += av[c] * fabsf(za);
      e1b += av[c + 4] * zb;   e2b += av[c + 4] * fabsf(zb);
    }
    float e = 0.6f * (e1a + e1b) + 0.4f * (e2a + e2b);
    if (e > m + 25.f) {
      float sc = __expf(m - e);
      s *= sc;
      #pragma unroll
      for (int c = 0; c < 8; c++) nu[c] *= sc;
      m = e;
    }
    float pe = __expf(e - m);
    s += pe;
    #pragma unroll
    for (int c = 0; c < 8; c++) nu[c] += pe * xlv[c];
  };

  int i = beg + sub;
  int i3 = i + 24;
  int x3 = 0;
  uint4 r0, r1, r2;
  if (i < end)      r0 = reinterpret_cast<const uint4*>(xlb)[csr_src[i]];
  if (i + 8 < end)  r1 = reinterpret_cast<const uint4*>(xlb)[csr_src[i + 8]];
  if (i + 16 < end) r2 = reinterpret_cast<const uint4*>(xlb)[csr_src[i + 16]];
  if (i3 < end) x3 = csr_src[i3];

  #define STEP2(RR)                                                   \
    if (i >= end) break;                                              \
    PROCESS(RR);                                                      \
    if (i3 < end) RR = reinterpret_cast<const uint4*>(xlb)[x3];       \
    i += 8; i3 += 8;                                                  \
    if (i3 < end) x3 = csr_src[i3];

  for (;;) {
    STEP2(r0)
    STEP2(r1)
    STEP2(r2)
  }
  #undef STEP2

  float M = oct_max(m);
  float sc = __expf(m - M);
  float S = oct_sum(s * sc);
  float o[8];
  #pragma unroll
  for (int c = 0; c < 8; c++) o[c] = oct_sum(nu[c] * sc);
  float inv = 1.f / fmaxf(S, 1e-16f);
  // each lane writes its own channel: 8 consecutive floats/node -> coalesced
  out[(long)node * 8 + sub] = fmaxf(o[sub] * inv + bias[sub], 0.f);
}

// ---------------- fused mean pool + linear: one block per graph ----------------
__global__ __launch_bounds__(256) void k_pool_final(const float* __restrict__ h,
    const int* __restrict__ batch, const float* __restrict__ Wlin,
    const float* __restrict__ blin, float* __restrict__ out, int n) {
  int g = blockIdx.x;
  int lo = 0, hi = n;
  while (lo < hi) { int mid = (lo + hi) >> 1; if (batch[mid] < g) lo = mid + 1; else hi = mid; }
  int beg = lo;
  hi = n;
  while (lo < hi) { int mid = (lo + hi) >> 1; if (batch[mid] < g + 1) lo = mid + 1; else hi = mid; }
  int end = lo;

  float w[8];
  #pragma unroll
  for (int c = 0; c < 8; c++) w[c] = Wlin[c];

  float acc = 0.f;
  int t = threadIdx.x;
  for (int i = beg + t; i < end; i += 256) {
    const float4* hp = reinterpret_cast<const float4*>(h + (long)i * 8);
    float4 v0 = hp[0], v1 = hp[1];
    acc += v0.x * w[0] + v0.y * w[1] + v0.z * w[2] + v0.w * w[3]
         + v1.x * w[4] + v1.y * w[5] + v1.z * w[6] + v1.w * w[7];
  }
  #pragma unroll
  for (int off = 32; off; off >>= 1) acc += __shfl_down(acc, off, 64);
  __shared__ float sh[4];
  if ((t & 63) == 0) sh[t >> 6] = acc;
  __syncthreads();
  if (t == 0) {
    float total = sh[0] + sh[1] + sh[2] + sh[3];
    float cnt = (float)(end - beg);
    out[g] = total / fmaxf(cnt, 1.f) + blin[0];
  }
}

extern "C" void kernel_launch(void* const* d_in, const int* in_sizes, int n_in,
                              void* d_out, int out_size, void* d_ws, size_t ws_size,
                              hipStream_t stream) {
  (void)n_in; (void)ws_size;
  const float* x    = (const float*)d_in[0];
  const int*   ei   = (const int*)d_in[1];
  const int*   batch= (const int*)d_in[2];
  const float* W1l  = (const float*)d_in[3];
  const float* W1r  = (const float*)d_in[4];
  const float* a1   = (const float*)d_in[5];
  const float* b1   = (const float*)d_in[6];
  const float* W2l  = (const float*)d_in[7];
  const float* W2r  = (const float*)d_in[8];
  const float* a2   = (const float*)d_in[9];
  const float* b2   = (const float*)d_in[10];
  const float* Wlin = (const float*)d_in[11];
  const float* blin = (const float*)d_in[12];
  float* out = (float*)d_out;

  int N = in_sizes[0] / 128;
  int E = in_sizes[1] / 2;
  int G = out_size;                 // 256 graphs
  int ET = E + N;                   // edges incl self loops
  int NBu = (N + 255) >> 8;         // used buckets (256 nodes each), <= NBS
  int chunk = (ET + NBLK - 1) / NBLK;
  int nA = NBS * NBLK;              // 131072

  char* ws = (char*)d_ws;
  size_t off = 0;
  auto alloc = [&](size_t bytes) {
    void* p = ws + off; off = (off + bytes + 255) & ~(size_t)255; return p;
  };
  int* csr_ptr = (int*)alloc((size_t)(N + 1) * 4);
  int* A       = (int*)alloc((size_t)(nA + 1) * 4);
  int* bsum    = (int*)alloc(512 * 4);
  int* csr_src = (int*)alloc((size_t)ET * 4);
  // union: packed pairs (ET*4 B) time-shared with feature buffers (N*176 B)
  size_t featBytes = (size_t)N * (32 + 64 + 16 + 32 + 32);
  size_t pairBytes = (size_t)ET * 4;
  char* u = (char*)alloc(pairBytes > featBytes ? pairBytes : featBytes);
  int* pairs = (int*)u;
  unsigned* xl1b = (unsigned*)u;                         // N*8 uints (bf16 x16)
  float* xr1     = (float*)(u + (size_t)N * 32);         // N*16 f32
  unsigned* xl2b = (unsigned*)(u + (size_t)N * 96);      // N*4 uints (bf16 x8)
  float* xr2     = (float*)(u + (size_t)N * 112);        // N*8 f32
  float* h2      = (float*)(u + (size_t)N * 144);        // N*8 f32

  k_bin_count<<<NBLK, 1024, 0, stream>>>(ei, E, ET, chunk, A);
  k_reduce4<<<nA / 1024, 256, 0, stream>>>(A, bsum, nA);
  k_scan_bsum<<<1, 512, 0, stream>>>(bsum, nA / 1024);
  k_scan_apply4<<<nA / 1024, 256, 0, stream>>>(A, bsum, nA);
  k_bin_scatter<<<NBLK, 1024, 0, stream>>>(ei, E, ET, chunk, A, pairs);
  k_csr_build<<<NBu, 1024, 0, stream>>>(pairs, A, csr_ptr, csr_src, N, NBu);
  k_gemm1<<<(N + 63) / 64, 256, 0, stream>>>(x, W1l, W1r, xl1b, xr1, N);
  k_edge1<<<(N + 31) / 32, 256, 0, stream>>>(csr_ptr, csr_src, xl1b, xr1, a1, b1,
                                             W2l, W2r, xl2b, xr2, N);
  k_edge2<<<(N + 31) / 32, 256, 0, stream>>>(csr_ptr, csr_src, xl2b, xr2, a2, b2, h2, N);
  k_pool_final<<<G, 256, 0, stream>>>(h2, batch, Wlin, blin, out, N);
}